// Round 1
// baseline (2441.621 us; speedup 1.0000x reference)
//
#include <hip/hip_runtime.h>
#include <hip/hip_bf16.h>

typedef __bf16 bf16;
typedef __attribute__((ext_vector_type(8))) __bf16 bf16x8;
typedef __attribute__((ext_vector_type(4))) float floatx4;

#define HDIM 512
#define BATCH 4096
#define TSTEPS 16
#define FDIM 64
#define KA 576      // padded A width: 63 x-feats + 512 h + 1 zero pad
#define ZLD 2560    // Z buffer row: 2048 gates + 512 tg  (hWa cols split off)

__device__ __forceinline__ float sigm(float x) { return 1.0f / (1.0f + expf(-x)); }

__device__ __forceinline__ float waveAllSum(float v) {
#pragma unroll
  for (int off = 32; off > 0; off >>= 1) v += __shfl_xor(v, off, 64);
  return v;
}

// ---------------------------------------------------------------------------
// bf16 MFMA GEMM: C[M,N] = A[M,K] * B[K,N], B given transposed (BT[N,K]).
// M multiple of BM (always 4096 here), N multiple of BN, K multiple of 32.
// mode 0: f32 store (+optional col bias); cols >= split go to outB as bf16
// mode 2: v = tanh(v + extraF[m*extraLd+n] + cBias2[n]) -> bf16 to outB & outB2
// mode 3: v = relu(v + cBias2[n]) -> bf16 to outB
// ---------------------------------------------------------------------------
template <int BM, int BN>
__global__ __launch_bounds__(256)
void gemm_bf16_kernel(const bf16* __restrict__ A, const bf16* __restrict__ BT, int K,
                      int mode, float* __restrict__ outF, int ldF,
                      const float* __restrict__ colBias,
                      bf16* __restrict__ outB, int ldB, bf16* __restrict__ outB2,
                      int split, const float* __restrict__ extraF, int extraLd,
                      const float* __restrict__ cBias2) {
  constexpr int BK = 32;
  constexpr int LDST = BK + 8;  // +8 bf16 pad: row stride 80B -> conflict-free b128 reads
  constexpr int WM = BM / 2;
  constexpr int WN = BN / 2;
  constexpr int TM = WM / 16;
  constexpr int TN = WN / 16;
  __shared__ __align__(16) bf16 As[BM * LDST];
  __shared__ __align__(16) bf16 Bs[BN * LDST];

  const int tid = threadIdx.x;
  const int lane = tid & 63;
  const int wave = tid >> 6;
  const int wy = wave >> 1;
  const int wx = wave & 1;
  const int quad = lane >> 4;
  const int lr = lane & 15;
  const int m0 = blockIdx.y * BM;
  const int n0 = blockIdx.x * BN;

  floatx4 acc[TM][TN];
#pragma unroll
  for (int i = 0; i < TM; ++i)
#pragma unroll
    for (int j = 0; j < TN; ++j) {
      acc[i][j][0] = 0.f; acc[i][j][1] = 0.f; acc[i][j][2] = 0.f; acc[i][j][3] = 0.f;
    }

  const int kTiles = K / BK;
  constexpr int ACH = (BM * BK / 8) / 256;
  constexpr int BCH = (BN * BK / 8) / 256;

  for (int kt = 0; kt < kTiles; ++kt) {
    const int kb = kt * BK;
    __syncthreads();
#pragma unroll
    for (int i = 0; i < ACH; ++i) {
      int idx = tid + i * 256;
      int row = idx >> 2;          // BK/8 = 4 chunks per row
      int c8 = (idx & 3) * 8;
      bf16x8 v = *reinterpret_cast<const bf16x8*>(A + (size_t)(m0 + row) * K + kb + c8);
      *reinterpret_cast<bf16x8*>(&As[row * LDST + c8]) = v;
    }
#pragma unroll
    for (int i = 0; i < BCH; ++i) {
      int idx = tid + i * 256;
      int row = idx >> 2;
      int c8 = (idx & 3) * 8;
      bf16x8 v = *reinterpret_cast<const bf16x8*>(BT + (size_t)(n0 + row) * K + kb + c8);
      *reinterpret_cast<bf16x8*>(&Bs[row * LDST + c8]) = v;
    }
    __syncthreads();
    bf16x8 afr[TM];
    bf16x8 bfr[TN];
#pragma unroll
    for (int i = 0; i < TM; ++i)
      afr[i] = *reinterpret_cast<const bf16x8*>(&As[(wy * WM + i * 16 + lr) * LDST + quad * 8]);
#pragma unroll
    for (int j = 0; j < TN; ++j)
      bfr[j] = *reinterpret_cast<const bf16x8*>(&Bs[(wx * WN + j * 16 + lr) * LDST + quad * 8]);
#pragma unroll
    for (int i = 0; i < TM; ++i)
#pragma unroll
      for (int j = 0; j < TN; ++j)
        acc[i][j] = __builtin_amdgcn_mfma_f32_16x16x32_bf16(afr[i], bfr[j], acc[i][j], 0, 0, 0);
  }

#pragma unroll
  for (int i = 0; i < TM; ++i) {
#pragma unroll
    for (int j = 0; j < TN; ++j) {
#pragma unroll
      for (int r = 0; r < 4; ++r) {
        int m = m0 + wy * WM + i * 16 + quad * 4 + r;
        int n = n0 + wx * WN + j * 16 + lr;
        float v = acc[i][j][r];
        if (mode == 0) {
          if (outB != nullptr && n >= split) {
            outB[(size_t)m * ldB + (n - split)] = (bf16)v;
          } else {
            if (colBias != nullptr) v += colBias[n];
            outF[(size_t)m * ldF + n] = v;
          }
        } else if (mode == 2) {
          v = tanhf(v + extraF[(size_t)m * extraLd + n] + cBias2[n]);
          bf16 hv = (bf16)v;
          outB[(size_t)m * ldB + n] = hv;
          outB2[(size_t)m * ldB + n] = hv;
        } else {  // mode 3
          v += cBias2[n];
          v = v > 0.f ? v : 0.f;
          outB[(size_t)m * ldB + n] = (bf16)v;
        }
      }
    }
  }
}

// ---------------------------------------------------------------------------
// Weight packing (runs every call; d_ws is re-poisoned by harness)
// ---------------------------------------------------------------------------
// WcombT[n][j], n<3072 rows, j<576:  columns of [x | h | pad] -> [z(2048) | tg(512) | hWa(512)]
__global__ void pack_wcombT_kernel(const float* __restrict__ Wx, const float* __restrict__ Uh,
                                   const float* __restrict__ WxT, const float* __restrict__ Wa,
                                   bf16* __restrict__ out) {
  int idx = blockIdx.x * 256 + threadIdx.x;
  if (idx >= 3072 * KA) return;
  int n = idx / KA;
  int j = idx - n * KA;
  float v = 0.f;
  if (n < 2048) {
    if (j < 63) v = Wx[j * 2048 + n];
    else if (j < 575) v = Uh[(j - 63) * 2048 + n];
  } else if (n < 2560) {
    if (j < 63) v = WxT[j * 512 + (n - 2048)];
  } else {
    if (j >= 63 && j < 575) v = Wa[(j - 63) * 512 + (n - 2560)];
  }
  out[idx] = (bf16)v;
}

// generic transpose-pack: out[n*K + j] = in[j*N + n]  (in is [K,N] f32, out [N,K] bf16)
__global__ void pack_t_kernel(const float* __restrict__ in, bf16* __restrict__ out, int N, int K) {
  int idx = blockIdx.x * 256 + threadIdx.x;
  if (idx >= N * K) return;
  int n = idx / K;
  int j = idx - n * K;
  out[idx] = (bf16)in[(size_t)j * N + n];
}

// s[h] = sum_f init_proj[f,h]; sWa[h'] = sum_h s[h]*Wa[h,h']; baPad = [ba | 0]
__global__ __launch_bounds__(512)
void setup_misc_kernel(const float* __restrict__ init_proj, const float* __restrict__ Wa,
                       const float* __restrict__ ba, float* __restrict__ sVec,
                       float* __restrict__ sWa, float* __restrict__ baPad) {
  __shared__ float s_sh[HDIM];
  int h = threadIdx.x;
  float acc = 0.f;
  for (int f = 0; f < FDIM; ++f) acc += init_proj[f * HDIM + h];
  s_sh[h] = acc;
  sVec[h] = acc;
  baPad[h] = ba[h];
  baPad[HDIM + h] = 0.f;
  __syncthreads();
  float a2 = 0.f;
  for (int i = 0; i < HDIM; ++i) a2 += s_sh[i] * Wa[i * HDIM + h];
  sWa[h] = a2;
}

__global__ void zero_state_kernel(float* __restrict__ c, bf16* __restrict__ h) {
  int idx = blockIdx.x * 256 + threadIdx.x;
  if (idx >= BATCH * HDIM) return;
  c[idx] = 0.f;
  h[idx] = (bf16)0.f;
}

// A_step[b, 0:63] = x_t, [63:575] = h, [575] = 0
__global__ void build_A_kernel(const float* __restrict__ inputs, const bf16* __restrict__ h,
                               bf16* __restrict__ A, int t) {
  int idx = blockIdx.x * 256 + threadIdx.x;
  if (idx >= BATCH * KA) return;
  int b = idx / KA;
  int j = idx - b * KA;
  bf16 v;
  if (j < 63) v = (bf16)inputs[(size_t)b * (TSTEPS * FDIM) + t * FDIM + 1 + j];
  else if (j < 575) v = h[(size_t)b * HDIM + (j - 63)];
  else v = (bf16)0.f;
  A[idx] = v;
}

// gates: from Z[B,2560] (zi zf zo zc tg), td, c -> c_new (f32), h_cur (bf16)
__global__ __launch_bounds__(256)
void gates_kernel(const float* __restrict__ Z, const float* __restrict__ inputs,
                  const float* __restrict__ bvec, const float* __restrict__ Wt,
                  const float* __restrict__ WtT, const float* __restrict__ bT,
                  float* __restrict__ c, bf16* __restrict__ h_cur, int t) {
  int idx = blockIdx.x * 256 + threadIdx.x;  // grid sized exactly B*H
  int b = idx >> 9;
  int h = idx & 511;
  float td = inputs[(size_t)b * (TSTEPS * FDIM) + t * FDIM];
  const float* z = Z + (size_t)b * ZLD;
  float i_ = sigm(z[h] + bvec[h] + td * Wt[h]);
  float f_ = sigm(z[512 + h] + bvec[512 + h] + td * Wt[512 + h]);
  float o_ = sigm(z[1024 + h] + bvec[1024 + h] + td * Wt[1024 + h]);
  float ch = tanhf(z[1536 + h] + bvec[1536 + h]);
  float tg = sigm(z[2048 + h] + sigm(td * WtT[h]) + bT[h]);
  float cn = f_ * c[idx] + i_ * ch + tg * ch;
  c[idx] = cn;
  h_cur[idx] = (bf16)(o_ * tanhf(cn));
}

// attention over memory: k active hist slots + (15-k) identical init slots
__global__ __launch_bounds__(64)
void attention_kernel(const float* __restrict__ hWbG,  // [B,1024]: [hWb+ba | hWg]
                      const float* __restrict__ sWa, const float* __restrict__ sVec,
                      const float* __restrict__ va, const bf16* __restrict__ hist_h,
                      const bf16* __restrict__ hist_hWa, bf16* __restrict__ ctx, int k) {
  int b = blockIdx.x;
  int lane = threadIdx.x;  // 64 lanes, each owns h in [lane*8, lane*8+8)
  float wb[8], sw[8], vv[8];
  const float* wbp = hWbG + (size_t)b * 1024 + lane * 8;
#pragma unroll
  for (int i = 0; i < 8; ++i) {
    wb[i] = wbp[i];
    sw[i] = sWa[lane * 8 + i];
    vv[i] = va[lane * 8 + i];
  }
  float p = 0.f;
#pragma unroll
  for (int i = 0; i < 8; ++i) p += vv[i] * tanhf(sw[i] + wb[i]);
  float e_init = waveAllSum(p);

  float e[15];
#pragma unroll
  for (int j = 0; j < 15; ++j) {
    if (j < k) {
      const bf16* hw = hist_hWa + ((size_t)j * BATCH + b) * HDIM + lane * 8;
      float q = 0.f;
#pragma unroll
      for (int i = 0; i < 8; ++i) q += vv[i] * tanhf((float)hw[i] + wb[i]);
      e[j] = waveAllSum(q);
    }
  }
  float mx = (k < 15) ? e_init : -1e30f;
#pragma unroll
  for (int j = 0; j < 15; ++j)
    if (j < k) mx = fmaxf(mx, e[j]);
  float winit = (k < 15) ? (float)(15 - k) * expf(e_init - mx) : 0.f;
  float denom = winit;
  float w[15];
#pragma unroll
  for (int j = 0; j < 15; ++j) {
    if (j < k) { w[j] = expf(e[j] - mx); denom += w[j]; }
  }
  float inv = 1.f / denom;
  float cx[8];
  float ai = winit * inv;
#pragma unroll
  for (int i = 0; i < 8; ++i) cx[i] = ai * sVec[lane * 8 + i];
#pragma unroll
  for (int j = 0; j < 15; ++j) {
    if (j < k) {
      const bf16* hh = hist_h + ((size_t)j * BATCH + b) * HDIM + lane * 8;
      float aj = w[j] * inv;
#pragma unroll
      for (int i = 0; i < 8; ++i) cx[i] += aj * (float)hh[i];
    }
  }
  bf16* cp = ctx + (size_t)b * HDIM + lane * 8;
#pragma unroll
  for (int i = 0; i < 8; ++i) cp[i] = (bf16)cx[i];
}

// head tail: hd2 = relu(hd1@W2+b2); out = softmax(hd2@W3+b3)
__global__ __launch_bounds__(256)
void head_kernel(const bf16* __restrict__ hd1, const float* __restrict__ W2,
                 const float* __restrict__ b2, const float* __restrict__ W3,
                 const float* __restrict__ b3, float* __restrict__ out) {
  __shared__ float W2s[256 * 32];
  __shared__ float b2s[32];
  __shared__ float W3s[64];
  __shared__ float b3s[2];
  for (int i = threadIdx.x; i < 256 * 32; i += 256) W2s[i] = W2[i];
  if (threadIdx.x < 32) b2s[threadIdx.x] = b2[threadIdx.x];
  if (threadIdx.x < 64) W3s[threadIdx.x] = W3[threadIdx.x];
  if (threadIdx.x < 2) b3s[threadIdx.x] = b3[threadIdx.x];
  __syncthreads();
  int row = blockIdx.x * 256 + threadIdx.x;  // grid 16 -> rows 0..4095
  float acc[32];
#pragma unroll
  for (int j = 0; j < 32; ++j) acc[j] = b2s[j];
  const bf16* hp = hd1 + (size_t)row * 256;
  for (int i = 0; i < 256; ++i) {
    float hv = (float)hp[i];
#pragma unroll
    for (int j = 0; j < 32; ++j) acc[j] += hv * W2s[i * 32 + j];
  }
  float l0 = b3s[0], l1 = b3s[1];
#pragma unroll
  for (int j = 0; j < 32; ++j) {
    float r = fmaxf(acc[j], 0.f);
    l0 += r * W3s[j * 2];
    l1 += r * W3s[j * 2 + 1];
  }
  float m = fmaxf(l0, l1);
  float e0 = expf(l0 - m), e1 = expf(l1 - m);
  float inv = 1.f / (e0 + e1);
  out[(size_t)row * 2] = e0 * inv;
  out[(size_t)row * 2 + 1] = e1 * inv;
}

// ---------------------------------------------------------------------------
extern "C" void kernel_launch(void* const* d_in, const int* in_sizes, int n_in,
                              void* d_out, int out_size, void* d_ws, size_t ws_size,
                              hipStream_t stream) {
  const float* inputs    = (const float*)d_in[0];
  const float* init_proj = (const float*)d_in[1];
  // d_in[2] = hc_init (zeros) -- state is zero-initialized directly
  const float* Wx  = (const float*)d_in[3];
  const float* Uh  = (const float*)d_in[4];
  const float* Wt  = (const float*)d_in[5];
  const float* bv  = (const float*)d_in[6];
  const float* WxT = (const float*)d_in[7];
  const float* WtT = (const float*)d_in[8];
  const float* bT  = (const float*)d_in[9];
  const float* Wa  = (const float*)d_in[10];
  const float* Wb  = (const float*)d_in[11];
  const float* va  = (const float*)d_in[12];
  const float* ba  = (const float*)d_in[13];
  const float* We  = (const float*)d_in[14];
  const float* Wg  = (const float*)d_in[15];
  const float* bh  = (const float*)d_in[16];
  const float* W1  = (const float*)d_in[17];
  const float* b1  = (const float*)d_in[18];
  const float* W2  = (const float*)d_in[19];
  const float* b2  = (const float*)d_in[20];
  const float* W3  = (const float*)d_in[21];
  const float* b3  = (const float*)d_in[22];
  float* out = (float*)d_out;

  char* wp = (char*)d_ws;
  auto carve = [&](size_t bytes) -> void* {
    void* p = (void*)wp;
    wp += (bytes + 255) & ~(size_t)255;
    return p;
  };
  bf16* wcombT = (bf16*)carve((size_t)3072 * KA * 2);
  bf16* wbwgT  = (bf16*)carve((size_t)1024 * 512 * 2);
  bf16* weT    = (bf16*)carve((size_t)512 * 512 * 2);
  bf16* w1T    = (bf16*)carve((size_t)256 * 512 * 2);
  float* sVec  = (float*)carve(512 * 4);
  float* sWa   = (float*)carve(512 * 4);
  float* baPad = (float*)carve(1024 * 4);
  bf16* Abuf   = (bf16*)carve((size_t)BATCH * KA * 2);
  float* Z     = (float*)carve((size_t)BATCH * ZLD * 4);
  float* cbuf  = (float*)carve((size_t)BATCH * HDIM * 4);
  bf16* hbf    = (bf16*)carve((size_t)BATCH * HDIM * 2);
  bf16* hcur   = (bf16*)carve((size_t)BATCH * HDIM * 2);
  bf16* ctxb   = (bf16*)carve((size_t)BATCH * HDIM * 2);
  float* hWbG  = (float*)carve((size_t)BATCH * 1024 * 4);
  bf16* hist_h = (bf16*)carve((size_t)16 * BATCH * HDIM * 2);
  bf16* histWa = (bf16*)carve((size_t)16 * BATCH * HDIM * 2);
  bf16* hd1    = (bf16*)carve((size_t)BATCH * 256 * 2);

  // ---- setup (every call: ws re-poisoned) ----
  pack_wcombT_kernel<<<(3072 * KA + 255) / 256, 256, 0, stream>>>(Wx, Uh, WxT, Wa, wcombT);
  pack_t_kernel<<<(512 * 512) / 256, 256, 0, stream>>>(Wb, wbwgT, 512, 512);
  pack_t_kernel<<<(512 * 512) / 256, 256, 0, stream>>>(Wg, wbwgT + (size_t)512 * 512, 512, 512);
  pack_t_kernel<<<(512 * 512) / 256, 256, 0, stream>>>(We, weT, 512, 512);
  pack_t_kernel<<<(256 * 512) / 256, 256, 0, stream>>>(W1, w1T, 256, 512);
  setup_misc_kernel<<<1, 512, 0, stream>>>(init_proj, Wa, ba, sVec, sWa, baPad);
  zero_state_kernel<<<(BATCH * HDIM + 255) / 256, 256, 0, stream>>>(cbuf, hbf);

  // ---- recurrence ----
  for (int t = 0; t < TSTEPS; ++t) {
    build_A_kernel<<<(BATCH * KA + 255) / 256, 256, 0, stream>>>(inputs, hbf, Abuf, t);
    // Z[:,0:2560] f32; cols 2560..3071 = (incoming h)@Wa -> histWa slot (t-1 mod 16)
    bf16* waSlot = histWa + (size_t)((t + 15) & 15) * BATCH * HDIM;
    gemm_bf16_kernel<128, 128><<<dim3(3072 / 128, BATCH / 128), 256, 0, stream>>>(
        Abuf, wcombT, KA, 0, Z, ZLD, nullptr, waSlot, HDIM, nullptr, ZLD, nullptr, 0, nullptr);
    gates_kernel<<<(BATCH * HDIM) / 256, 256, 0, stream>>>(Z, inputs, bv, Wt, WtT, bT, cbuf,
                                                           hcur, t);
    // [hWb+ba | hWg] = h_cur @ [Wb|Wg] + [ba|0]
    gemm_bf16_kernel<128, 128><<<dim3(1024 / 128, BATCH / 128), 256, 0, stream>>>(
        hcur, wbwgT, 512, 0, hWbG, 1024, baPad, nullptr, 0, nullptr, 1 << 30, nullptr, 0,
        nullptr);
    attention_kernel<<<BATCH, 64, 0, stream>>>(hWbG, sWa, sVec, va, hist_h, histWa, ctxb, t);
    // h_new = tanh(ctx@We + hWg + bh) -> hbf and hist_h[t]
    gemm_bf16_kernel<128, 128><<<dim3(512 / 128, BATCH / 128), 256, 0, stream>>>(
        ctxb, weT, 512, 2, nullptr, 0, nullptr, hbf, HDIM, hist_h + (size_t)t * BATCH * HDIM, 0,
        hWbG + 512, 1024, bh);
  }

  // ---- head ----
  gemm_bf16_kernel<128, 128><<<dim3(256 / 128, BATCH / 128), 256, 0, stream>>>(
      hbf, w1T, 512, 3, nullptr, 0, nullptr, hd1, 256, nullptr, 0, nullptr, 0, b1);
  head_kernel<<<BATCH / 256, 256, 0, stream>>>(hd1, W2, b2, W3, b3, out);
}

// Round 2
// 2290.748 us; speedup vs baseline: 1.0659x; 1.0659x over previous
//
#include <hip/hip_runtime.h>
#include <hip/hip_bf16.h>

typedef __bf16 bf16;
typedef __attribute__((ext_vector_type(8))) __bf16 bf16x8;
typedef __attribute__((ext_vector_type(4))) float floatx4;

#define HDIM 512
#define BATCH 4096
#define TSTEPS 16
#define FDIM 64
#define KA 576      // padded A width: 63 x-feats + 512 h + 1 zero pad
#define ZLD 2560    // Z buffer row: 2048 gates + 512 tg  (hWa cols split off)

// fast transcendentals: v_exp_f32-based, ~1e-7 rel err (invisible under bf16)
__device__ __forceinline__ float ftanh(float x) {
  float xx = fminf(fmaxf(x, -15.f), 15.f);
  float t = __expf(2.f * xx);
  return (t - 1.f) / (t + 1.f);
}
__device__ __forceinline__ float fsigm(float x) { return 1.0f / (1.0f + __expf(-x)); }

__device__ __forceinline__ float waveAllSum(float v) {
#pragma unroll
  for (int off = 32; off > 0; off >>= 1) v += __shfl_xor(v, off, 64);
  return v;
}

// ---------------------------------------------------------------------------
// bf16 MFMA GEMM: C[M,N] = A[M,K] * B[K,N], B given transposed (BT[N,K]).
// mode 0: f32 store (+optional col bias); cols >= split go to outB as bf16
// mode 2: v = tanh(v + extraF[m*extraLd+n] + cBias2[n]) -> bf16 to outB & outB2
// mode 3: v = relu(v + cBias2[n]) -> bf16 to outB
// ---------------------------------------------------------------------------
template <int BM, int BN>
__global__ __launch_bounds__(256)
void gemm_bf16_kernel(const bf16* __restrict__ A, const bf16* __restrict__ BT, int K,
                      int mode, float* __restrict__ outF, int ldF,
                      const float* __restrict__ colBias,
                      bf16* __restrict__ outB, int ldB, bf16* __restrict__ outB2,
                      int split, const float* __restrict__ extraF, int extraLd,
                      const float* __restrict__ cBias2) {
  constexpr int BK = 32;
  constexpr int LDST = BK + 8;  // +8 bf16 pad: row stride 80B -> conflict-free b128 reads
  constexpr int WM = BM / 2;
  constexpr int WN = BN / 2;
  constexpr int TM = WM / 16;
  constexpr int TN = WN / 16;
  __shared__ __align__(16) bf16 As[BM * LDST];
  __shared__ __align__(16) bf16 Bs[BN * LDST];

  const int tid = threadIdx.x;
  const int lane = tid & 63;
  const int wave = tid >> 6;
  const int wy = wave >> 1;
  const int wx = wave & 1;
  const int quad = lane >> 4;
  const int lr = lane & 15;
  const int m0 = blockIdx.y * BM;
  const int n0 = blockIdx.x * BN;

  floatx4 acc[TM][TN];
#pragma unroll
  for (int i = 0; i < TM; ++i)
#pragma unroll
    for (int j = 0; j < TN; ++j) {
      acc[i][j][0] = 0.f; acc[i][j][1] = 0.f; acc[i][j][2] = 0.f; acc[i][j][3] = 0.f;
    }

  const int kTiles = K / BK;
  constexpr int ACH = (BM * BK / 8) / 256;
  constexpr int BCH = (BN * BK / 8) / 256;

  for (int kt = 0; kt < kTiles; ++kt) {
    const int kb = kt * BK;
    __syncthreads();
#pragma unroll
    for (int i = 0; i < ACH; ++i) {
      int idx = tid + i * 256;
      int row = idx >> 2;          // BK/8 = 4 chunks per row
      int c8 = (idx & 3) * 8;
      bf16x8 v = *reinterpret_cast<const bf16x8*>(A + (size_t)(m0 + row) * K + kb + c8);
      *reinterpret_cast<bf16x8*>(&As[row * LDST + c8]) = v;
    }
#pragma unroll
    for (int i = 0; i < BCH; ++i) {
      int idx = tid + i * 256;
      int row = idx >> 2;
      int c8 = (idx & 3) * 8;
      bf16x8 v = *reinterpret_cast<const bf16x8*>(BT + (size_t)(n0 + row) * K + kb + c8);
      *reinterpret_cast<bf16x8*>(&Bs[row * LDST + c8]) = v;
    }
    __syncthreads();
    bf16x8 afr[TM];
    bf16x8 bfr[TN];
#pragma unroll
    for (int i = 0; i < TM; ++i)
      afr[i] = *reinterpret_cast<const bf16x8*>(&As[(wy * WM + i * 16 + lr) * LDST + quad * 8]);
#pragma unroll
    for (int j = 0; j < TN; ++j)
      bfr[j] = *reinterpret_cast<const bf16x8*>(&Bs[(wx * WN + j * 16 + lr) * LDST + quad * 8]);
#pragma unroll
    for (int i = 0; i < TM; ++i)
#pragma unroll
      for (int j = 0; j < TN; ++j)
        acc[i][j] = __builtin_amdgcn_mfma_f32_16x16x32_bf16(afr[i], bfr[j], acc[i][j], 0, 0, 0);
  }

#pragma unroll
  for (int i = 0; i < TM; ++i) {
#pragma unroll
    for (int j = 0; j < TN; ++j) {
#pragma unroll
      for (int r = 0; r < 4; ++r) {
        int m = m0 + wy * WM + i * 16 + quad * 4 + r;
        int n = n0 + wx * WN + j * 16 + lr;
        float v = acc[i][j][r];
        if (mode == 0) {
          if (outB != nullptr && n >= split) {
            outB[(size_t)m * ldB + (n - split)] = (bf16)v;
          } else {
            if (colBias != nullptr) v += colBias[n];
            outF[(size_t)m * ldF + n] = v;
          }
        } else if (mode == 2) {
          v = ftanh(v + extraF[(size_t)m * extraLd + n] + cBias2[n]);
          bf16 hv = (bf16)v;
          outB[(size_t)m * ldB + n] = hv;
          outB2[(size_t)m * ldB + n] = hv;
        } else {  // mode 3
          v += cBias2[n];
          v = v > 0.f ? v : 0.f;
          outB[(size_t)m * ldB + n] = (bf16)v;
        }
      }
    }
  }
}

// ---------------------------------------------------------------------------
// Weight packing (runs every call; d_ws is re-poisoned by harness)
// ---------------------------------------------------------------------------
__global__ void pack_wcombT_kernel(const float* __restrict__ Wx, const float* __restrict__ Uh,
                                   const float* __restrict__ WxT, const float* __restrict__ Wa,
                                   bf16* __restrict__ out) {
  int idx = blockIdx.x * 256 + threadIdx.x;
  if (idx >= 3072 * KA) return;
  int n = idx / KA;
  int j = idx - n * KA;
  float v = 0.f;
  if (n < 2048) {
    if (j < 63) v = Wx[j * 2048 + n];
    else if (j < 575) v = Uh[(j - 63) * 2048 + n];
  } else if (n < 2560) {
    if (j < 63) v = WxT[j * 512 + (n - 2048)];
  } else {
    if (j >= 63 && j < 575) v = Wa[(j - 63) * 512 + (n - 2560)];
  }
  out[idx] = (bf16)v;
}

__global__ void pack_t_kernel(const float* __restrict__ in, bf16* __restrict__ out, int N, int K) {
  int idx = blockIdx.x * 256 + threadIdx.x;
  if (idx >= N * K) return;
  int n = idx / K;
  int j = idx - n * K;
  out[idx] = (bf16)in[(size_t)j * N + n];
}

__global__ __launch_bounds__(512)
void setup_misc_kernel(const float* __restrict__ init_proj, const float* __restrict__ Wa,
                       const float* __restrict__ ba, float* __restrict__ sVec,
                       float* __restrict__ sWa, float* __restrict__ baPad) {
  __shared__ float s_sh[HDIM];
  int h = threadIdx.x;
  float acc = 0.f;
  for (int f = 0; f < FDIM; ++f) acc += init_proj[f * HDIM + h];
  s_sh[h] = acc;
  sVec[h] = acc;
  baPad[h] = ba[h];
  baPad[HDIM + h] = 0.f;
  __syncthreads();
  float a2 = 0.f;
  for (int i = 0; i < HDIM; ++i) a2 += s_sh[i] * Wa[i * HDIM + h];
  sWa[h] = a2;
}

__global__ void zero_state_kernel(float* __restrict__ c, bf16* __restrict__ h) {
  int idx = blockIdx.x * 256 + threadIdx.x;
  if (idx >= BATCH * HDIM) return;
  c[idx] = 0.f;
  h[idx] = (bf16)0.f;
}

__global__ void build_A_kernel(const float* __restrict__ inputs, const bf16* __restrict__ h,
                               bf16* __restrict__ A, int t) {
  int idx = blockIdx.x * 256 + threadIdx.x;
  if (idx >= BATCH * KA) return;
  int b = idx / KA;
  int j = idx - b * KA;
  bf16 v;
  if (j < 63) v = (bf16)inputs[(size_t)b * (TSTEPS * FDIM) + t * FDIM + 1 + j];
  else if (j < 575) v = h[(size_t)b * HDIM + (j - 63)];
  else v = (bf16)0.f;
  A[idx] = v;
}

__global__ __launch_bounds__(256)
void gates_kernel(const float* __restrict__ Z, const float* __restrict__ inputs,
                  const float* __restrict__ bvec, const float* __restrict__ Wt,
                  const float* __restrict__ WtT, const float* __restrict__ bT,
                  float* __restrict__ c, bf16* __restrict__ h_cur, int t) {
  int idx = blockIdx.x * 256 + threadIdx.x;  // grid sized exactly B*H
  int b = idx >> 9;
  int h = idx & 511;
  float td = inputs[(size_t)b * (TSTEPS * FDIM) + t * FDIM];
  const float* z = Z + (size_t)b * ZLD;
  float i_ = fsigm(z[h] + bvec[h] + td * Wt[h]);
  float f_ = fsigm(z[512 + h] + bvec[512 + h] + td * Wt[512 + h]);
  float o_ = fsigm(z[1024 + h] + bvec[1024 + h] + td * Wt[1024 + h]);
  float ch = ftanh(z[1536 + h] + bvec[1536 + h]);
  float tg = fsigm(z[2048 + h] + fsigm(td * WtT[h]) + bT[h]);
  float cn = f_ * c[idx] + i_ * ch + tg * ch;
  c[idx] = cn;
  h_cur[idx] = (bf16)(o_ * ftanh(cn));
}

// attention over memory: k active hist slots + (15-k) identical init slots.
// 256 threads = 4 waves; each wave owns one batch row (grid = BATCH/4).
__global__ __launch_bounds__(256)
void attention_kernel(const float* __restrict__ hWbG,  // [B,1024]: [hWb+ba | hWg]
                      const float* __restrict__ sWa, const float* __restrict__ sVec,
                      const float* __restrict__ va, const bf16* __restrict__ hist_h,
                      const bf16* __restrict__ hist_hWa, bf16* __restrict__ ctx, int k) {
  int b = blockIdx.x * 4 + (threadIdx.x >> 6);
  int lane = threadIdx.x & 63;  // each lane owns h in [lane*8, lane*8+8)
  float wb[8], sw[8], vv[8];
  const float* wbp = hWbG + (size_t)b * 1024 + lane * 8;
#pragma unroll
  for (int i = 0; i < 8; ++i) {
    wb[i] = wbp[i];
    sw[i] = sWa[lane * 8 + i];
    vv[i] = va[lane * 8 + i];
  }
  float p = 0.f;
#pragma unroll
  for (int i = 0; i < 8; ++i) p += vv[i] * ftanh(sw[i] + wb[i]);
  float e_init = waveAllSum(p);

  float e[15];
#pragma unroll
  for (int j = 0; j < 15; ++j) {
    if (j < k) {
      const bf16* hw = hist_hWa + ((size_t)j * BATCH + b) * HDIM + lane * 8;
      bf16x8 hv = *reinterpret_cast<const bf16x8*>(hw);
      float q = 0.f;
#pragma unroll
      for (int i = 0; i < 8; ++i) q += vv[i] * ftanh((float)hv[i] + wb[i]);
      e[j] = waveAllSum(q);
    }
  }
  float mx = (k < 15) ? e_init : -1e30f;
#pragma unroll
  for (int j = 0; j < 15; ++j)
    if (j < k) mx = fmaxf(mx, e[j]);
  float winit = (k < 15) ? (float)(15 - k) * __expf(e_init - mx) : 0.f;
  float denom = winit;
  float w[15];
#pragma unroll
  for (int j = 0; j < 15; ++j) {
    if (j < k) { w[j] = __expf(e[j] - mx); denom += w[j]; }
  }
  float inv = 1.f / denom;
  float cx[8];
  float ai = winit * inv;
#pragma unroll
  for (int i = 0; i < 8; ++i) cx[i] = ai * sVec[lane * 8 + i];
#pragma unroll
  for (int j = 0; j < 15; ++j) {
    if (j < k) {
      const bf16* hh = hist_h + ((size_t)j * BATCH + b) * HDIM + lane * 8;
      bf16x8 hv = *reinterpret_cast<const bf16x8*>(hh);
      float aj = w[j] * inv;
#pragma unroll
      for (int i = 0; i < 8; ++i) cx[i] += aj * (float)hv[i];
    }
  }
  bf16* cp = ctx + (size_t)b * HDIM + lane * 8;
#pragma unroll
  for (int i = 0; i < 8; ++i) cp[i] = (bf16)cx[i];
}

// head tail: hd2 = relu(hd1@W2+b2); out = softmax(hd2@W3+b3)
__global__ __launch_bounds__(256)
void head_kernel(const bf16* __restrict__ hd1, const float* __restrict__ W2,
                 const float* __restrict__ b2, const float* __restrict__ W3,
                 const float* __restrict__ b3, float* __restrict__ out) {
  __shared__ float W2s[256 * 32];
  __shared__ float b2s[32];
  __shared__ float W3s[64];
  __shared__ float b3s[2];
  for (int i = threadIdx.x; i < 256 * 32; i += 256) W2s[i] = W2[i];
  if (threadIdx.x < 32) b2s[threadIdx.x] = b2[threadIdx.x];
  if (threadIdx.x < 64) W3s[threadIdx.x] = W3[threadIdx.x];
  if (threadIdx.x < 2) b3s[threadIdx.x] = b3[threadIdx.x];
  __syncthreads();
  int row = blockIdx.x * 256 + threadIdx.x;
  float acc[32];
#pragma unroll
  for (int j = 0; j < 32; ++j) acc[j] = b2s[j];
  const bf16* hp = hd1 + (size_t)row * 256;
  for (int i = 0; i < 256; ++i) {
    float hv = (float)hp[i];
#pragma unroll
    for (int j = 0; j < 32; ++j) acc[j] += hv * W2s[i * 32 + j];
  }
  float l0 = b3s[0], l1 = b3s[1];
#pragma unroll
  for (int j = 0; j < 32; ++j) {
    float r = fmaxf(acc[j], 0.f);
    l0 += r * W3s[j * 2];
    l1 += r * W3s[j * 2 + 1];
  }
  float m = fmaxf(l0, l1);
  float e0 = __expf(l0 - m), e1 = __expf(l1 - m);
  float inv = 1.f / (e0 + e1);
  out[(size_t)row * 2] = e0 * inv;
  out[(size_t)row * 2 + 1] = e1 * inv;
}

// ---------------------------------------------------------------------------
extern "C" void kernel_launch(void* const* d_in, const int* in_sizes, int n_in,
                              void* d_out, int out_size, void* d_ws, size_t ws_size,
                              hipStream_t stream) {
  const float* inputs    = (const float*)d_in[0];
  const float* init_proj = (const float*)d_in[1];
  const float* Wx  = (const float*)d_in[3];
  const float* Uh  = (const float*)d_in[4];
  const float* Wt  = (const float*)d_in[5];
  const float* bv  = (const float*)d_in[6];
  const float* WxT = (const float*)d_in[7];
  const float* WtT = (const float*)d_in[8];
  const float* bT  = (const float*)d_in[9];
  const float* Wa  = (const float*)d_in[10];
  const float* Wb  = (const float*)d_in[11];
  const float* va  = (const float*)d_in[12];
  const float* ba  = (const float*)d_in[13];
  const float* We  = (const float*)d_in[14];
  const float* Wg  = (const float*)d_in[15];
  const float* bh  = (const float*)d_in[16];
  const float* W1  = (const float*)d_in[17];
  const float* b1  = (const float*)d_in[18];
  const float* W2  = (const float*)d_in[19];
  const float* b2  = (const float*)d_in[20];
  const float* W3  = (const float*)d_in[21];
  const float* b3  = (const float*)d_in[22];
  float* out = (float*)d_out;

  char* wp = (char*)d_ws;
  auto carve = [&](size_t bytes) -> void* {
    void* p = (void*)wp;
    wp += (bytes + 255) & ~(size_t)255;
    return p;
  };
  bf16* wcombT = (bf16*)carve((size_t)3072 * KA * 2);
  bf16* wbwgT  = (bf16*)carve((size_t)1024 * 512 * 2);
  bf16* weT    = (bf16*)carve((size_t)512 * 512 * 2);
  bf16* w1T    = (bf16*)carve((size_t)256 * 512 * 2);
  float* sVec  = (float*)carve(512 * 4);
  float* sWa   = (float*)carve(512 * 4);
  float* baPad = (float*)carve(1024 * 4);
  bf16* Abuf   = (bf16*)carve((size_t)BATCH * KA * 2);
  float* Z     = (float*)carve((size_t)BATCH * ZLD * 4);
  float* cbuf  = (float*)carve((size_t)BATCH * HDIM * 4);
  bf16* hbf    = (bf16*)carve((size_t)BATCH * HDIM * 2);
  bf16* hcur   = (bf16*)carve((size_t)BATCH * HDIM * 2);
  bf16* ctxb   = (bf16*)carve((size_t)BATCH * HDIM * 2);
  float* hWbG  = (float*)carve((size_t)BATCH * 1024 * 4);
  bf16* hist_h = (bf16*)carve((size_t)16 * BATCH * HDIM * 2);
  bf16* histWa = (bf16*)carve((size_t)16 * BATCH * HDIM * 2);
  bf16* hd1    = (bf16*)carve((size_t)BATCH * 256 * 2);

  // ---- setup (every call: ws re-poisoned) ----
  pack_wcombT_kernel<<<(3072 * KA + 255) / 256, 256, 0, stream>>>(Wx, Uh, WxT, Wa, wcombT);
  pack_t_kernel<<<(512 * 512) / 256, 256, 0, stream>>>(Wb, wbwgT, 512, 512);
  pack_t_kernel<<<(512 * 512) / 256, 256, 0, stream>>>(Wg, wbwgT + (size_t)512 * 512, 512, 512);
  pack_t_kernel<<<(512 * 512) / 256, 256, 0, stream>>>(We, weT, 512, 512);
  pack_t_kernel<<<(256 * 512) / 256, 256, 0, stream>>>(W1, w1T, 256, 512);
  setup_misc_kernel<<<1, 512, 0, stream>>>(init_proj, Wa, ba, sVec, sWa, baPad);
  zero_state_kernel<<<(BATCH * HDIM + 255) / 256, 256, 0, stream>>>(cbuf, hbf);

  // ---- recurrence ----
  for (int t = 0; t < TSTEPS; ++t) {
    build_A_kernel<<<(BATCH * KA + 255) / 256, 256, 0, stream>>>(inputs, hbf, Abuf, t);
    bf16* waSlot = histWa + (size_t)((t + 15) & 15) * BATCH * HDIM;
    gemm_bf16_kernel<128, 128><<<dim3(3072 / 128, BATCH / 128), 256, 0, stream>>>(
        Abuf, wcombT, KA, 0, Z, ZLD, nullptr, waSlot, HDIM, nullptr, ZLD, nullptr, 0, nullptr);
    gates_kernel<<<(BATCH * HDIM) / 256, 256, 0, stream>>>(Z, inputs, bv, Wt, WtT, bT, cbuf,
                                                           hcur, t);
    gemm_bf16_kernel<128, 128><<<dim3(1024 / 128, BATCH / 128), 256, 0, stream>>>(
        hcur, wbwgT, 512, 0, hWbG, 1024, baPad, nullptr, 0, nullptr, 1 << 30, nullptr, 0,
        nullptr);
    attention_kernel<<<BATCH / 4, 256, 0, stream>>>(hWbG, sWa, sVec, va, hist_h, histWa, ctxb, t);
    gemm_bf16_kernel<128, 128><<<dim3(512 / 128, BATCH / 128), 256, 0, stream>>>(
        ctxb, weT, 512, 2, nullptr, 0, nullptr, hbf, HDIM, hist_h + (size_t)t * BATCH * HDIM, 0,
        hWbG + 512, 1024, bh);
  }

  // ---- head ----
  gemm_bf16_kernel<128, 128><<<dim3(256 / 128, BATCH / 128), 256, 0, stream>>>(
      hbf, w1T, 512, 3, nullptr, 0, nullptr, hd1, 256, nullptr, 0, nullptr, 0, b1);
  head_kernel<<<BATCH / 256, 256, 0, stream>>>(hd1, W2, b2, W3, b3, out);
}

// Round 3
// 1671.485 us; speedup vs baseline: 1.4607x; 1.3705x over previous
//
#include <hip/hip_runtime.h>
#include <hip/hip_bf16.h>

typedef __bf16 bf16;
typedef __attribute__((ext_vector_type(8))) __bf16 bf16x8;
typedef __attribute__((ext_vector_type(4))) float floatx4;

#define HDIM 512
#define BATCH 4096
#define TSTEPS 16
#define KA 576      // A width: 64 x-cols (63 feats + 1 zero pad) + 512 h
#define NCOMB 3584  // GEMM1 out: 2048 gates + 512 tg + 512 hWa + 512 hWe
#define ZLD 2560    // f32 part of GEMM1 out

typedef const __attribute__((address_space(1))) void gvoid;
typedef __attribute__((address_space(3))) void svoid;

__device__ __forceinline__ float ftanh(float x) {
  float xx = fminf(fmaxf(x, -15.f), 15.f);
  float t = __expf(2.f * xx);
  return (t - 1.f) / (t + 1.f);
}
__device__ __forceinline__ float fsigm(float x) { return 1.0f / (1.0f + __expf(-x)); }

__device__ __forceinline__ float waveAllSum(float v) {
#pragma unroll
  for (int off = 32; off > 0; off >>= 1) v += __shfl_xor(v, off, 64);
  return v;
}

// ---------------------------------------------------------------------------
// MFMA GEMM with global_load_lds(16B) staging + XOR-swizzled LDS layout.
// A is logically [A1(K1 cols, ld1) | A2(ld2)] row-major bf16 (per-lane gather).
// B given transposed: BT[N][K] bf16.
// mode 0: n<splitA -> f32 outF (+colBias); [splitA,splitB) -> bf16 outBa;
//         >=splitB -> bf16 outBe  (both ld = ldBa)
// mode 3: relu(v + cBias2[n]) -> bf16 outBa (ld = ldBa)
// LDS layout: row r (64B) holds logical chunk cl at physical chunk cl^((r>>1)&3).
// ---------------------------------------------------------------------------
template <int BM, int BN>
__global__ __launch_bounds__(256)
void gemm_glds_kernel(const bf16* __restrict__ A1, int ld1, int K1,
                      const bf16* __restrict__ A2, int ld2,
                      const bf16* __restrict__ BT, int K, int mode,
                      float* __restrict__ outF, int ldF, const float* __restrict__ colBias,
                      bf16* __restrict__ outBa, bf16* __restrict__ outBe, int ldBa,
                      int splitA, int splitB, const float* __restrict__ cBias2) {
  constexpr int BK = 32;
  constexpr int WM = BM / 2;
  constexpr int WN = BN / 2;
  constexpr int TM = WM / 16;
  constexpr int TN = WN / 16;
  constexpr int AIW = BM / 64;  // A glds instructions per wave (BM/16 total / 4 waves)
  constexpr int BIW = BN / 64;
  __shared__ __align__(16) bf16 As[BM * BK];
  __shared__ __align__(16) bf16 Bs[BN * BK];

  const int tid = threadIdx.x;
  const int lane = tid & 63;
  const int wv = tid >> 6;
  const int wy = wv >> 1;
  const int wx = wv & 1;
  const int quad = lane >> 4;
  const int lr = lane & 15;
  const int m0 = blockIdx.y * BM;
  const int n0 = blockIdx.x * BN;
  // fragment-read swizzle: logical quad of row rA lives at chunk quad^((rA>>1)&3);
  // rA low 4 bits == lr  ->  sw is lane-constant
  const int sw = quad ^ ((lr >> 1) & 3);
  // staging lane roles: lane covers physical row base+ (lane>>2), chunk lane&3
  const int srow = lane >> 2;
  const int cl = (lane & 3) ^ ((lane >> 3) & 3);  // logical chunk this lane fetches

  floatx4 acc[TM][TN];
#pragma unroll
  for (int i = 0; i < TM; ++i)
#pragma unroll
    for (int j = 0; j < TN; ++j) {
      acc[i][j][0] = 0.f; acc[i][j][1] = 0.f; acc[i][j][2] = 0.f; acc[i][j][3] = 0.f;
    }

  const int kTiles = K / BK;
  for (int kt = 0; kt < kTiles; ++kt) {
    const int kb = kt * BK;
    __syncthreads();
#pragma unroll
    for (int s = 0; s < AIW; ++s) {
      const int rbase = (wv * AIW + s) * 16;
      const int r = rbase + srow;
      const int col = kb + cl * 8;
      const bf16* src = (col < K1) ? (A1 + (size_t)(m0 + r) * ld1 + col)
                                   : (A2 + (size_t)(m0 + r) * ld2 + (col - K1));
      __builtin_amdgcn_global_load_lds((gvoid*)src, (svoid*)&As[rbase * BK], 16, 0, 0);
    }
#pragma unroll
    for (int s = 0; s < BIW; ++s) {
      const int rbase = (wv * BIW + s) * 16;
      const int r = rbase + srow;
      const bf16* src = BT + (size_t)(n0 + r) * K + kb + cl * 8;
      __builtin_amdgcn_global_load_lds((gvoid*)src, (svoid*)&Bs[rbase * BK], 16, 0, 0);
    }
    __syncthreads();
    bf16x8 afr[TM];
    bf16x8 bfr[TN];
#pragma unroll
    for (int i = 0; i < TM; ++i)
      afr[i] = *reinterpret_cast<const bf16x8*>(&As[(wy * WM + i * 16 + lr) * BK + sw * 8]);
#pragma unroll
    for (int j = 0; j < TN; ++j)
      bfr[j] = *reinterpret_cast<const bf16x8*>(&Bs[(wx * WN + j * 16 + lr) * BK + sw * 8]);
#pragma unroll
    for (int i = 0; i < TM; ++i)
#pragma unroll
      for (int j = 0; j < TN; ++j)
        acc[i][j] = __builtin_amdgcn_mfma_f32_16x16x32_bf16(afr[i], bfr[j], acc[i][j], 0, 0, 0);
  }

#pragma unroll
  for (int i = 0; i < TM; ++i) {
#pragma unroll
    for (int j = 0; j < TN; ++j) {
#pragma unroll
      for (int r = 0; r < 4; ++r) {
        int m = m0 + wy * WM + i * 16 + quad * 4 + r;
        int n = n0 + wx * WN + j * 16 + lr;
        float v = acc[i][j][r];
        if (mode == 0) {
          if (n >= splitB) {
            outBe[(size_t)m * ldBa + (n - splitB)] = (bf16)v;
          } else if (n >= splitA) {
            outBa[(size_t)m * ldBa + (n - splitA)] = (bf16)v;
          } else {
            if (colBias != nullptr) v += colBias[n];
            outF[(size_t)m * ldF + n] = v;
          }
        } else {  // mode 3
          v += cBias2[n];
          v = v > 0.f ? v : 0.f;
          outBa[(size_t)m * ldBa + n] = (bf16)v;
        }
      }
    }
  }
}

// ---------------------------------------------------------------------------
// Setup kernels (run every call; ws re-poisoned by harness)
// ---------------------------------------------------------------------------
// WcombT[n][j], n<3584, j<576. A cols: j<63 = x feats, j==63 = pad, j>=64 = h.
__global__ void pack_wcombT_kernel(const float* __restrict__ Wx, const float* __restrict__ Uh,
                                   const float* __restrict__ WxT, const float* __restrict__ Wa,
                                   const float* __restrict__ We, bf16* __restrict__ out) {
  int idx = blockIdx.x * 256 + threadIdx.x;
  if (idx >= NCOMB * KA) return;
  int n = idx / KA;
  int j = idx - n * KA;
  float v = 0.f;
  if (n < 2048) {
    if (j < 63) v = Wx[j * 2048 + n];
    else if (j >= 64) v = Uh[(j - 64) * 2048 + n];
  } else if (n < 2560) {
    if (j < 63) v = WxT[j * 512 + (n - 2048)];
  } else if (n < 3072) {
    if (j >= 64) v = Wa[(j - 64) * 512 + (n - 2560)];
  } else {
    if (j >= 64) v = We[(j - 64) * 512 + (n - 3072)];
  }
  out[idx] = (bf16)v;
}

__global__ void pack_t_kernel(const float* __restrict__ in, bf16* __restrict__ out, int N, int K) {
  int idx = blockIdx.x * 256 + threadIdx.x;
  if (idx >= N * K) return;
  int n = idx / K;
  int j = idx - n * K;
  out[idx] = (bf16)in[(size_t)j * N + n];
}

// s = colsum(init_proj); sWa = s@Wa; sWe = s@We; baPad = [ba|0]
__global__ __launch_bounds__(512)
void setup_misc_kernel(const float* __restrict__ init_proj, const float* __restrict__ Wa,
                       const float* __restrict__ We, const float* __restrict__ ba,
                       float* __restrict__ sVec, float* __restrict__ sWa,
                       float* __restrict__ sWe, float* __restrict__ baPad) {
  __shared__ float s_sh[HDIM];
  int h = threadIdx.x;
  float acc = 0.f;
  for (int f = 0; f < 64; ++f) acc += init_proj[f * HDIM + h];
  s_sh[h] = acc;
  sVec[h] = acc;
  baPad[h] = ba[h];
  baPad[HDIM + h] = 0.f;
  __syncthreads();
  float a2 = 0.f, a3 = 0.f;
  for (int i = 0; i < HDIM; ++i) {
    a2 += s_sh[i] * Wa[i * HDIM + h];
    a3 += s_sh[i] * We[i * HDIM + h];
  }
  sWa[h] = a2;
  sWe[h] = a3;
}

__global__ void zero_state_kernel(float* __restrict__ c, bf16* __restrict__ h) {
  int idx = blockIdx.x * 256 + threadIdx.x;
  if (idx >= BATCH * HDIM) return;
  c[idx] = 0.f;
  h[idx] = (bf16)0.f;
}

// xbuf[t][b][64]: cols 0..62 = features 1..63 at step t, col 63 = 0
__global__ void build_x_kernel(const float* __restrict__ inputs, bf16* __restrict__ xbuf) {
  int idx = blockIdx.x * 256 + threadIdx.x;
  if (idx >= TSTEPS * BATCH * 64) return;
  int c = idx & 63;
  int bt = idx >> 6;
  int t = bt >> 12;
  int b = bt & 4095;
  float v = (c < 63) ? inputs[(size_t)b * 1024 + t * 64 + 1 + c] : 0.f;
  xbuf[idx] = (bf16)v;
}

__global__ __launch_bounds__(256)
void gates_kernel(const float* __restrict__ Z, const float* __restrict__ inputs,
                  const float* __restrict__ bvec, const float* __restrict__ Wt,
                  const float* __restrict__ WtT, const float* __restrict__ bT,
                  float* __restrict__ c, bf16* __restrict__ h_cur, int t) {
  int idx = blockIdx.x * 256 + threadIdx.x;
  int b = idx >> 9;
  int h = idx & 511;
  float td = inputs[(size_t)b * 1024 + t * 64];
  const float* z = Z + (size_t)b * ZLD;
  float i_ = fsigm(z[h] + bvec[h] + td * Wt[h]);
  float f_ = fsigm(z[512 + h] + bvec[512 + h] + td * Wt[512 + h]);
  float o_ = fsigm(z[1024 + h] + bvec[1024 + h] + td * Wt[1024 + h]);
  float ch = ftanh(z[1536 + h] + bvec[1536 + h]);
  float tg = fsigm(z[2048 + h] + fsigm(td * WtT[h]) + bT[h]);
  float cn = f_ * c[idx] + i_ * ch + tg * ch;
  c[idx] = cn;
  h_cur[idx] = (bf16)(o_ * ftanh(cn));
}

// attention + h_new: scores from histWa, ctx@We from histWe, epilogue tanh.
// 4 waves/block, one batch row per wave.
__global__ __launch_bounds__(256)
void attention_kernel(const float* __restrict__ hWbG,  // [B,1024]: [hWb+ba | hWg]
                      const float* __restrict__ sWa, const float* __restrict__ sWe,
                      const float* __restrict__ va, const float* __restrict__ bh,
                      const bf16* __restrict__ histWa, const bf16* __restrict__ histWe,
                      bf16* __restrict__ hbuf, int k) {
  int b = blockIdx.x * 4 + (threadIdx.x >> 6);
  int lane = threadIdx.x & 63;  // lane owns h in [lane*8, lane*8+8)
  float wb[8], sw_[8], vv[8];
  const float* wbp = hWbG + (size_t)b * 1024 + lane * 8;
#pragma unroll
  for (int i = 0; i < 8; ++i) {
    wb[i] = wbp[i];
    sw_[i] = sWa[lane * 8 + i];
    vv[i] = va[lane * 8 + i];
  }
  float p = 0.f;
#pragma unroll
  for (int i = 0; i < 8; ++i) p += vv[i] * ftanh(sw_[i] + wb[i]);
  float e_init = waveAllSum(p);

  float e[15];
#pragma unroll
  for (int j = 0; j < 15; ++j) {
    if (j < k) {
      bf16x8 hv = *reinterpret_cast<const bf16x8*>(
          histWa + ((size_t)j * BATCH + b) * HDIM + lane * 8);
      float q = 0.f;
#pragma unroll
      for (int i = 0; i < 8; ++i) q += vv[i] * ftanh((float)hv[i] + wb[i]);
      e[j] = waveAllSum(q);
    }
  }
  float mx = (k < 15) ? e_init : -1e30f;
#pragma unroll
  for (int j = 0; j < 15; ++j)
    if (j < k) mx = fmaxf(mx, e[j]);
  float winit = (k < 15) ? (float)(15 - k) * __expf(e_init - mx) : 0.f;
  float denom = winit;
  float w[15];
#pragma unroll
  for (int j = 0; j < 15; ++j)
    if (j < k) { w[j] = __expf(e[j] - mx); denom += w[j]; }
  float inv = 1.f / denom;
  float cx[8];
  float ai = winit * inv;
#pragma unroll
  for (int i = 0; i < 8; ++i) cx[i] = ai * sWe[lane * 8 + i];
#pragma unroll
  for (int j = 0; j < 15; ++j) {
    if (j < k) {
      bf16x8 hv = *reinterpret_cast<const bf16x8*>(
          histWe + ((size_t)j * BATCH + b) * HDIM + lane * 8);
      float aj = w[j] * inv;
#pragma unroll
      for (int i = 0; i < 8; ++i) cx[i] += aj * (float)hv[i];
    }
  }
  // h_new = tanh(ctxWe + hWg + bh)
  bf16x8 hnew;
#pragma unroll
  for (int i = 0; i < 8; ++i)
    hnew[i] = (bf16)ftanh(cx[i] + wbp[512 + i] + bh[lane * 8 + i]);
  *reinterpret_cast<bf16x8*>(hbuf + (size_t)b * HDIM + lane * 8) = hnew;
}

__global__ __launch_bounds__(256)
void head_kernel(const bf16* __restrict__ hd1, const float* __restrict__ W2,
                 const float* __restrict__ b2, const float* __restrict__ W3,
                 const float* __restrict__ b3, float* __restrict__ out) {
  __shared__ float W2s[256 * 32];
  __shared__ float b2s[32];
  __shared__ float W3s[64];
  __shared__ float b3s[2];
  for (int i = threadIdx.x; i < 256 * 32; i += 256) W2s[i] = W2[i];
  if (threadIdx.x < 32) b2s[threadIdx.x] = b2[threadIdx.x];
  if (threadIdx.x < 64) W3s[threadIdx.x] = W3[threadIdx.x];
  if (threadIdx.x < 2) b3s[threadIdx.x] = b3[threadIdx.x];
  __syncthreads();
  int row = blockIdx.x * 256 + threadIdx.x;
  float acc[32];
#pragma unroll
  for (int j = 0; j < 32; ++j) acc[j] = b2s[j];
  const bf16* hp = hd1 + (size_t)row * 256;
  for (int i = 0; i < 256; ++i) {
    float hv = (float)hp[i];
#pragma unroll
    for (int j = 0; j < 32; ++j) acc[j] += hv * W2s[i * 32 + j];
  }
  float l0 = b3s[0], l1 = b3s[1];
#pragma unroll
  for (int j = 0; j < 32; ++j) {
    float r = fmaxf(acc[j], 0.f);
    l0 += r * W3s[j * 2];
    l1 += r * W3s[j * 2 + 1];
  }
  float m = fmaxf(l0, l1);
  float e0 = __expf(l0 - m), e1 = __expf(l1 - m);
  float inv = 1.f / (e0 + e1);
  out[(size_t)row * 2] = e0 * inv;
  out[(size_t)row * 2 + 1] = e1 * inv;
}

// ---------------------------------------------------------------------------
extern "C" void kernel_launch(void* const* d_in, const int* in_sizes, int n_in,
                              void* d_out, int out_size, void* d_ws, size_t ws_size,
                              hipStream_t stream) {
  const float* inputs    = (const float*)d_in[0];
  const float* init_proj = (const float*)d_in[1];
  const float* Wx  = (const float*)d_in[3];
  const float* Uh  = (const float*)d_in[4];
  const float* Wt  = (const float*)d_in[5];
  const float* bv  = (const float*)d_in[6];
  const float* WxT = (const float*)d_in[7];
  const float* WtT = (const float*)d_in[8];
  const float* bT  = (const float*)d_in[9];
  const float* Wa  = (const float*)d_in[10];
  const float* Wb  = (const float*)d_in[11];
  const float* va  = (const float*)d_in[12];
  const float* ba  = (const float*)d_in[13];
  const float* We  = (const float*)d_in[14];
  const float* Wg  = (const float*)d_in[15];
  const float* bh  = (const float*)d_in[16];
  const float* W1  = (const float*)d_in[17];
  const float* b1  = (const float*)d_in[18];
  const float* W2  = (const float*)d_in[19];
  const float* b2  = (const float*)d_in[20];
  const float* W3  = (const float*)d_in[21];
  const float* b3  = (const float*)d_in[22];
  float* out = (float*)d_out;

  char* wp = (char*)d_ws;
  auto carve = [&](size_t bytes) -> void* {
    void* p = (void*)wp;
    wp += (bytes + 255) & ~(size_t)255;
    return p;
  };
  bf16* wcombT = (bf16*)carve((size_t)NCOMB * KA * 2);
  bf16* wbwgT  = (bf16*)carve((size_t)1024 * 512 * 2);
  bf16* w1T    = (bf16*)carve((size_t)256 * 512 * 2);
  float* sVec  = (float*)carve(512 * 4);
  float* sWa   = (float*)carve(512 * 4);
  float* sWe   = (float*)carve(512 * 4);
  float* baPad = (float*)carve(1024 * 4);
  bf16* xbuf   = (bf16*)carve((size_t)TSTEPS * BATCH * 64 * 2);
  float* Z     = (float*)carve((size_t)BATCH * ZLD * 4);
  float* cbuf  = (float*)carve((size_t)BATCH * HDIM * 4);
  bf16* hbuf   = (bf16*)carve((size_t)BATCH * HDIM * 2);
  bf16* hcur   = (bf16*)carve((size_t)BATCH * HDIM * 2);
  float* hWbG  = (float*)carve((size_t)BATCH * 1024 * 4);
  bf16* histWa = (bf16*)carve((size_t)16 * BATCH * HDIM * 2);
  bf16* histWe = (bf16*)carve((size_t)16 * BATCH * HDIM * 2);
  bf16* hd1    = (bf16*)carve((size_t)BATCH * 256 * 2);

  // ---- setup ----
  build_x_kernel<<<(TSTEPS * BATCH * 64) / 256, 256, 0, stream>>>(inputs, xbuf);
  pack_wcombT_kernel<<<(NCOMB * KA + 255) / 256, 256, 0, stream>>>(Wx, Uh, WxT, Wa, We, wcombT);
  pack_t_kernel<<<(512 * 512) / 256, 256, 0, stream>>>(Wb, wbwgT, 512, 512);
  pack_t_kernel<<<(512 * 512) / 256, 256, 0, stream>>>(Wg, wbwgT + (size_t)512 * 512, 512, 512);
  pack_t_kernel<<<(256 * 512) / 256, 256, 0, stream>>>(W1, w1T, 256, 512);
  setup_misc_kernel<<<1, 512, 0, stream>>>(init_proj, Wa, We, ba, sVec, sWa, sWe, baPad);
  zero_state_kernel<<<(BATCH * HDIM) / 256, 256, 0, stream>>>(cbuf, hbuf);

  // ---- recurrence ----
  for (int t = 0; t < TSTEPS; ++t) {
    // GEMM1: [x_t | h] @ Wcomb -> Z f32 (gates+tg) | hWa slot | hWe slot (bf16)
    bf16* waSlot = histWa + (size_t)((t + 15) & 15) * BATCH * HDIM;
    bf16* weSlot = histWe + (size_t)((t + 15) & 15) * BATCH * HDIM;
    gemm_glds_kernel<128, 128><<<dim3(NCOMB / 128, BATCH / 128), 256, 0, stream>>>(
        xbuf + (size_t)t * BATCH * 64, 64, 64, hbuf, 512, wcombT, KA, 0,
        Z, ZLD, nullptr, waSlot, weSlot, HDIM, 2560, 3072, nullptr);
    gates_kernel<<<(BATCH * HDIM) / 256, 256, 0, stream>>>(Z, inputs, bv, Wt, WtT, bT, cbuf,
                                                           hcur, t);
    // [hWb+ba | hWg] = h_cur @ [Wb|Wg] + [ba|0]
    gemm_glds_kernel<64, 128><<<dim3(1024 / 128, BATCH / 64), 256, 0, stream>>>(
        hcur, 512, 512, hcur, 512, wbwgT, 512, 0,
        hWbG, 1024, baPad, nullptr, nullptr, 0, 1 << 30, 1 << 30, nullptr);
    attention_kernel<<<BATCH / 4, 256, 0, stream>>>(hWbG, sWa, sWe, va, bh, histWa, histWe,
                                                    hbuf, t);
  }

  // ---- head ----
  gemm_glds_kernel<64, 128><<<dim3(256 / 128, BATCH / 64), 256, 0, stream>>>(
      hbuf, 512, 512, hbuf, 512, w1T, 512, 3,
      nullptr, 0, nullptr, hd1, nullptr, 256, 0, 0, b1);
  head_kernel<<<BATCH / 256, 256, 0, stream>>>(hd1, W2, b2, W3, b3, out);
}

// Round 4
// 1585.769 us; speedup vs baseline: 1.5397x; 1.0541x over previous
//
#include <hip/hip_runtime.h>
#include <hip/hip_bf16.h>

typedef __bf16 bf16;
typedef __attribute__((ext_vector_type(8))) __bf16 bf16x8;
typedef __attribute__((ext_vector_type(4))) float floatx4;

#define HDIM 512
#define BATCH 4096
#define TSTEPS 16
#define KA 576      // A width: 63 x-feats + td + 512 h
#define NR 4096     // GEMM1 out cols: role-interleaved, 8 roles x 512 h

typedef const __attribute__((address_space(1))) void gvoid;
typedef __attribute__((address_space(3))) void svoid;

__device__ __forceinline__ float ftanh(float x) {
  float xx = fminf(fmaxf(x, -15.f), 15.f);
  float t = __expf(2.f * xx);
  return (t - 1.f) / (t + 1.f);
}
__device__ __forceinline__ float fsigm(float x) { return 1.0f / (1.0f + __expf(-x)); }

__device__ __forceinline__ float waveAllSum(float v) {
#pragma unroll
  for (int off = 32; off > 0; off >>= 1) v += __shfl_xor(v, off, 64);
  return v;
}

// ---------------------------------------------------------------------------
// Fused GEMM1 + gates. A = [x_t(63) | td | h(512)], B = role-interleaved WcombT.
// n bits: h = (n>>7)*16 + (n&15), role = (n>>4)&7:
//   0..3 = zi,zf,zo,zc (td*Wt folded via A col63), 4 = tg, 5 = hWa, 6 = hWe, 7 = pad
// BM=128, BN=256, waves 2x2 -> per lane acc[i][role][r]; gates fully in-register.
// ---------------------------------------------------------------------------
__global__ __launch_bounds__(256)
void gemm1_fused_kernel(const bf16* __restrict__ A1, const bf16* __restrict__ A2,
                        const bf16* __restrict__ BT,
                        const float* __restrict__ inputs, const float* __restrict__ bvec,
                        const float* __restrict__ WtT, const float* __restrict__ bT,
                        float* __restrict__ cbuf, bf16* __restrict__ hcur,
                        bf16* __restrict__ waSlot, bf16* __restrict__ weSlot, int t) {
  constexpr int BM = 128, BN = 256, BK = 32;
  constexpr int TM = 4, TN = 8;
  __shared__ __align__(16) bf16 As[BM * BK];
  __shared__ __align__(16) bf16 Bs[BN * BK];

  const int tid = threadIdx.x;
  const int lane = tid & 63;
  const int wv = tid >> 6;
  const int wy = wv >> 1;
  const int wx = wv & 1;
  const int quad = lane >> 4;
  const int lr = lane & 15;
  const int m0 = blockIdx.y * BM;
  const int n0 = blockIdx.x * BN;
  const int sw = quad ^ ((lr >> 1) & 3);
  const int srow = lane >> 2;
  const int cl = (lane & 3) ^ ((lane >> 3) & 3);

  floatx4 acc[TM][TN];
#pragma unroll
  for (int i = 0; i < TM; ++i)
#pragma unroll
    for (int j = 0; j < TN; ++j) {
      acc[i][j][0] = 0.f; acc[i][j][1] = 0.f; acc[i][j][2] = 0.f; acc[i][j][3] = 0.f;
    }

  for (int kt = 0; kt < KA / BK; ++kt) {
    const int kb = kt * BK;
    __syncthreads();
#pragma unroll
    for (int s = 0; s < 2; ++s) {  // A: 128 rows = 8 groups of 16, 2 per wave
      const int rbase = (wv * 2 + s) * 16;
      const int r = rbase + srow;
      const int col = kb + cl * 8;
      const bf16* src = (col < 64) ? (A1 + (size_t)(m0 + r) * 64 + col)
                                   : (A2 + (size_t)(m0 + r) * 512 + (col - 64));
      __builtin_amdgcn_global_load_lds((gvoid*)src, (svoid*)&As[rbase * BK], 16, 0, 0);
    }
#pragma unroll
    for (int s = 0; s < 4; ++s) {  // B: 256 rows = 16 groups, 4 per wave
      const int rbase = (wv * 4 + s) * 16;
      const int r = rbase + srow;
      const bf16* src = BT + (size_t)(n0 + r) * KA + kb + cl * 8;
      __builtin_amdgcn_global_load_lds((gvoid*)src, (svoid*)&Bs[rbase * BK], 16, 0, 0);
    }
    __syncthreads();
    bf16x8 afr[TM];
    bf16x8 bfr[TN];
#pragma unroll
    for (int i = 0; i < TM; ++i)
      afr[i] = *reinterpret_cast<const bf16x8*>(&As[(wy * 64 + i * 16 + lr) * BK + sw * 8]);
#pragma unroll
    for (int j = 0; j < TN; ++j)
      bfr[j] = *reinterpret_cast<const bf16x8*>(&Bs[(wx * 128 + j * 16 + lr) * BK + sw * 8]);
#pragma unroll
    for (int i = 0; i < TM; ++i)
#pragma unroll
      for (int j = 0; j < TN; ++j)
        acc[i][j] = __builtin_amdgcn_mfma_f32_16x16x32_bf16(afr[i], bfr[j], acc[i][j], 0, 0, 0);
  }

  // ---- fused gate epilogue: lane owns h; roles are the j index ----
  const int h = (blockIdx.x * 2 + wx) * 16 + lr;
  const float bvi = bvec[h], bvf = bvec[512 + h], bvo = bvec[1024 + h], bvc = bvec[1536 + h];
  const float wtt = WtT[h], bt_ = bT[h];
#pragma unroll
  for (int i = 0; i < TM; ++i) {
#pragma unroll
    for (int r = 0; r < 4; ++r) {
      const int m = m0 + wy * 64 + i * 16 + quad * 4 + r;
      const float td = inputs[(size_t)m * 1024 + t * 64];
      const size_t o = (size_t)m * 512 + h;
      const float c_old = cbuf[o];
      const float i_ = fsigm(acc[i][0][r] + bvi);
      const float f_ = fsigm(acc[i][1][r] + bvf);
      const float o_ = fsigm(acc[i][2][r] + bvo);
      const float ch = ftanh(acc[i][3][r] + bvc);
      const float tg = fsigm(acc[i][4][r] + fsigm(td * wtt) + bt_);
      const float cn = f_ * c_old + (i_ + tg) * ch;
      cbuf[o] = cn;
      hcur[o] = (bf16)(o_ * ftanh(cn));
      waSlot[o] = (bf16)acc[i][5][r];
      weSlot[o] = (bf16)acc[i][6][r];
    }
  }
}

// ---------------------------------------------------------------------------
// Generic MFMA GEMM (glds staging) for GEMM2 + head GEMM1.
// mode 0: f32 out (+colBias); mode 3: relu(v+cBias2) -> bf16
// ---------------------------------------------------------------------------
template <int BM, int BN>
__global__ __launch_bounds__(256)
void gemm_glds_kernel(const bf16* __restrict__ A1, int ld1, int K1,
                      const bf16* __restrict__ A2, int ld2,
                      const bf16* __restrict__ BT, int K, int mode,
                      float* __restrict__ outF, int ldF, const float* __restrict__ colBias,
                      bf16* __restrict__ outBa, int ldBa, const float* __restrict__ cBias2) {
  constexpr int BK = 32;
  constexpr int WM = BM / 2;
  constexpr int WN = BN / 2;
  constexpr int TM = WM / 16;
  constexpr int TN = WN / 16;
  constexpr int AIW = BM / 64;
  constexpr int BIW = BN / 64;
  __shared__ __align__(16) bf16 As[BM * BK];
  __shared__ __align__(16) bf16 Bs[BN * BK];

  const int tid = threadIdx.x;
  const int lane = tid & 63;
  const int wv = tid >> 6;
  const int wy = wv >> 1;
  const int wx = wv & 1;
  const int quad = lane >> 4;
  const int lr = lane & 15;
  const int m0 = blockIdx.y * BM;
  const int n0 = blockIdx.x * BN;
  const int sw = quad ^ ((lr >> 1) & 3);
  const int srow = lane >> 2;
  const int cl = (lane & 3) ^ ((lane >> 3) & 3);

  floatx4 acc[TM][TN];
#pragma unroll
  for (int i = 0; i < TM; ++i)
#pragma unroll
    for (int j = 0; j < TN; ++j) {
      acc[i][j][0] = 0.f; acc[i][j][1] = 0.f; acc[i][j][2] = 0.f; acc[i][j][3] = 0.f;
    }

  const int kTiles = K / BK;
  for (int kt = 0; kt < kTiles; ++kt) {
    const int kb = kt * BK;
    __syncthreads();
#pragma unroll
    for (int s = 0; s < AIW; ++s) {
      const int rbase = (wv * AIW + s) * 16;
      const int r = rbase + srow;
      const int col = kb + cl * 8;
      const bf16* src = (col < K1) ? (A1 + (size_t)(m0 + r) * ld1 + col)
                                   : (A2 + (size_t)(m0 + r) * ld2 + (col - K1));
      __builtin_amdgcn_global_load_lds((gvoid*)src, (svoid*)&As[rbase * BK], 16, 0, 0);
    }
#pragma unroll
    for (int s = 0; s < BIW; ++s) {
      const int rbase = (wv * BIW + s) * 16;
      const int r = rbase + srow;
      const bf16* src = BT + (size_t)(n0 + r) * K + kb + cl * 8;
      __builtin_amdgcn_global_load_lds((gvoid*)src, (svoid*)&Bs[rbase * BK], 16, 0, 0);
    }
    __syncthreads();
    bf16x8 afr[TM];
    bf16x8 bfr[TN];
#pragma unroll
    for (int i = 0; i < TM; ++i)
      afr[i] = *reinterpret_cast<const bf16x8*>(&As[(wy * WM + i * 16 + lr) * BK + sw * 8]);
#pragma unroll
    for (int j = 0; j < TN; ++j)
      bfr[j] = *reinterpret_cast<const bf16x8*>(&Bs[(wx * WN + j * 16 + lr) * BK + sw * 8]);
#pragma unroll
    for (int i = 0; i < TM; ++i)
#pragma unroll
      for (int j = 0; j < TN; ++j)
        acc[i][j] = __builtin_amdgcn_mfma_f32_16x16x32_bf16(afr[i], bfr[j], acc[i][j], 0, 0, 0);
  }

#pragma unroll
  for (int i = 0; i < TM; ++i) {
#pragma unroll
    for (int j = 0; j < TN; ++j) {
#pragma unroll
      for (int r = 0; r < 4; ++r) {
        int m = m0 + wy * WM + i * 16 + quad * 4 + r;
        int n = n0 + wx * WN + j * 16 + lr;
        float v = acc[i][j][r];
        if (mode == 0) {
          if (colBias != nullptr) v += colBias[n];
          outF[(size_t)m * ldF + n] = v;
        } else {
          v += cBias2[n];
          v = v > 0.f ? v : 0.f;
          outBa[(size_t)m * ldBa + n] = (bf16)v;
        }
      }
    }
  }
}

// ---------------------------------------------------------------------------
// Setup kernels (run every call; ws re-poisoned by harness)
// ---------------------------------------------------------------------------
// Role-interleaved WcombT[n][k]: h=(n>>7)*16+(n&15), role=(n>>4)&7
__global__ void pack_wcombT_kernel(const float* __restrict__ Wx, const float* __restrict__ Uh,
                                   const float* __restrict__ Wt, const float* __restrict__ WxT,
                                   const float* __restrict__ Wa, const float* __restrict__ We,
                                   bf16* __restrict__ out) {
  int idx = blockIdx.x * 256 + threadIdx.x;
  if (idx >= NR * KA) return;
  int n = idx / KA;
  int k = idx - n * KA;
  int h = (n >> 7) * 16 + (n & 15);
  int role = (n >> 4) & 7;
  float v = 0.f;
  if (k < 63) {
    if (role < 4) v = Wx[k * 2048 + role * 512 + h];
    else if (role == 4) v = WxT[k * 512 + h];
  } else if (k == 63) {
    if (role < 3) v = Wt[role * 512 + h];
  } else {
    int kh = k - 64;
    if (role < 4) v = Uh[kh * 2048 + role * 512 + h];
    else if (role == 5) v = Wa[kh * 512 + h];
    else if (role == 6) v = We[kh * 512 + h];
  }
  out[idx] = (bf16)v;
}

__global__ void pack_t_kernel(const float* __restrict__ in, bf16* __restrict__ out, int N, int K) {
  int idx = blockIdx.x * 256 + threadIdx.x;
  if (idx >= N * K) return;
  int n = idx / K;
  int j = idx - n * K;
  out[idx] = (bf16)in[(size_t)j * N + n];
}

// s = colsum(init_proj); sWa = s@Wa; sWe = s@We; baPad = [ba|0]
__global__ __launch_bounds__(512)
void setup_misc_kernel(const float* __restrict__ init_proj, const float* __restrict__ Wa,
                       const float* __restrict__ We, const float* __restrict__ ba,
                       float* __restrict__ sWa, float* __restrict__ sWe,
                       float* __restrict__ baPad) {
  __shared__ float s_sh[HDIM];
  int h = threadIdx.x;
  float acc = 0.f;
  for (int f = 0; f < 64; ++f) acc += init_proj[f * HDIM + h];
  s_sh[h] = acc;
  baPad[h] = ba[h];
  baPad[HDIM + h] = 0.f;
  __syncthreads();
  float a2 = 0.f, a3 = 0.f;
  for (int i = 0; i < HDIM; ++i) {
    a2 += s_sh[i] * Wa[i * HDIM + h];
    a3 += s_sh[i] * We[i * HDIM + h];
  }
  sWa[h] = a2;
  sWe[h] = a3;
}

__global__ void zero_state_kernel(float* __restrict__ c, bf16* __restrict__ h) {
  int idx = blockIdx.x * 256 + threadIdx.x;
  if (idx >= BATCH * HDIM) return;
  c[idx] = 0.f;
  h[idx] = (bf16)0.f;
}

// xbuf[t][b][64]: cols 0..62 = feats 1..63, col 63 = td (time delta)
__global__ void build_x_kernel(const float* __restrict__ inputs, bf16* __restrict__ xbuf) {
  int idx = blockIdx.x * 256 + threadIdx.x;
  if (idx >= TSTEPS * BATCH * 64) return;
  int c = idx & 63;
  int bt = idx >> 6;
  int t = bt >> 12;
  int b = bt & 4095;
  float v = (c < 63) ? inputs[(size_t)b * 1024 + t * 64 + 1 + c]
                     : inputs[(size_t)b * 1024 + t * 64];
  xbuf[idx] = (bf16)v;
}

// attention + h_new epilogue; 4 waves/block, one batch row per wave
__global__ __launch_bounds__(256)
void attention_kernel(const float* __restrict__ hWbG,  // [B,1024]: [hWb+ba | hWg]
                      const float* __restrict__ sWa, const float* __restrict__ sWe,
                      const float* __restrict__ va, const float* __restrict__ bh,
                      const bf16* __restrict__ histWa, const bf16* __restrict__ histWe,
                      bf16* __restrict__ hbuf, int k) {
  int b = blockIdx.x * 4 + (threadIdx.x >> 6);
  int lane = threadIdx.x & 63;
  float wb[8], sw_[8], vv[8];
  const float* wbp = hWbG + (size_t)b * 1024 + lane * 8;
#pragma unroll
  for (int i = 0; i < 8; ++i) {
    wb[i] = wbp[i];
    sw_[i] = sWa[lane * 8 + i];
    vv[i] = va[lane * 8 + i];
  }
  float p = 0.f;
#pragma unroll
  for (int i = 0; i < 8; ++i) p += vv[i] * ftanh(sw_[i] + wb[i]);
  float e_init = waveAllSum(p);

  float e[15];
#pragma unroll
  for (int j = 0; j < 15; ++j) {
    if (j < k) {
      bf16x8 hv = *reinterpret_cast<const bf16x8*>(
          histWa + ((size_t)j * BATCH + b) * HDIM + lane * 8);
      float q = 0.f;
#pragma unroll
      for (int i = 0; i < 8; ++i) q += vv[i] * ftanh((float)hv[i] + wb[i]);
      e[j] = waveAllSum(q);
    }
  }
  float mx = (k < 15) ? e_init : -1e30f;
#pragma unroll
  for (int j = 0; j < 15; ++j)
    if (j < k) mx = fmaxf(mx, e[j]);
  float winit = (k < 15) ? (float)(15 - k) * __expf(e_init - mx) : 0.f;
  float denom = winit;
  float w[15];
#pragma unroll
  for (int j = 0; j < 15; ++j)
    if (j < k) { w[j] = __expf(e[j] - mx); denom += w[j]; }
  float inv = 1.f / denom;
  float cx[8];
  float ai = winit * inv;
#pragma unroll
  for (int i = 0; i < 8; ++i) cx[i] = ai * sWe[lane * 8 + i];
#pragma unroll
  for (int j = 0; j < 15; ++j) {
    if (j < k) {
      bf16x8 hv = *reinterpret_cast<const bf16x8*>(
          histWe + ((size_t)j * BATCH + b) * HDIM + lane * 8);
      float aj = w[j] * inv;
#pragma unroll
      for (int i = 0; i < 8; ++i) cx[i] += aj * (float)hv[i];
    }
  }
  bf16x8 hnew;
#pragma unroll
  for (int i = 0; i < 8; ++i)
    hnew[i] = (bf16)ftanh(cx[i] + wbp[512 + i] + bh[lane * 8 + i]);
  *reinterpret_cast<bf16x8*>(hbuf + (size_t)b * HDIM + lane * 8) = hnew;
}

__global__ __launch_bounds__(256)
void head_kernel(const bf16* __restrict__ hd1, const float* __restrict__ W2,
                 const float* __restrict__ b2, const float* __restrict__ W3,
                 const float* __restrict__ b3, float* __restrict__ out) {
  __shared__ float W2s[256 * 32];
  __shared__ float b2s[32];
  __shared__ float W3s[64];
  __shared__ float b3s[2];
  for (int i = threadIdx.x; i < 256 * 32; i += 256) W2s[i] = W2[i];
  if (threadIdx.x < 32) b2s[threadIdx.x] = b2[threadIdx.x];
  if (threadIdx.x < 64) W3s[threadIdx.x] = W3[threadIdx.x];
  if (threadIdx.x < 2) b3s[threadIdx.x] = b3[threadIdx.x];
  __syncthreads();
  int row = blockIdx.x * 256 + threadIdx.x;
  float acc[32];
#pragma unroll
  for (int j = 0; j < 32; ++j) acc[j] = b2s[j];
  const bf16* hp = hd1 + (size_t)row * 256;
  for (int i = 0; i < 256; ++i) {
    float hv = (float)hp[i];
#pragma unroll
    for (int j = 0; j < 32; ++j) acc[j] += hv * W2s[i * 32 + j];
  }
  float l0 = b3s[0], l1 = b3s[1];
#pragma unroll
  for (int j = 0; j < 32; ++j) {
    float r = fmaxf(acc[j], 0.f);
    l0 += r * W3s[j * 2];
    l1 += r * W3s[j * 2 + 1];
  }
  float m = fmaxf(l0, l1);
  float e0 = __expf(l0 - m), e1 = __expf(l1 - m);
  float inv = 1.f / (e0 + e1);
  out[(size_t)row * 2] = e0 * inv;
  out[(size_t)row * 2 + 1] = e1 * inv;
}

// ---------------------------------------------------------------------------
extern "C" void kernel_launch(void* const* d_in, const int* in_sizes, int n_in,
                              void* d_out, int out_size, void* d_ws, size_t ws_size,
                              hipStream_t stream) {
  const float* inputs    = (const float*)d_in[0];
  const float* init_proj = (const float*)d_in[1];
  const float* Wx  = (const float*)d_in[3];
  const float* Uh  = (const float*)d_in[4];
  const float* Wt  = (const float*)d_in[5];
  const float* bv  = (const float*)d_in[6];
  const float* WxT = (const float*)d_in[7];
  const float* WtT = (const float*)d_in[8];
  const float* bT  = (const float*)d_in[9];
  const float* Wa  = (const float*)d_in[10];
  const float* Wb  = (const float*)d_in[11];
  const float* va  = (const float*)d_in[12];
  const float* ba  = (const float*)d_in[13];
  const float* We  = (const float*)d_in[14];
  const float* Wg  = (const float*)d_in[15];
  const float* bh  = (const float*)d_in[16];
  const float* W1  = (const float*)d_in[17];
  const float* b1  = (const float*)d_in[18];
  const float* W2  = (const float*)d_in[19];
  const float* b2  = (const float*)d_in[20];
  const float* W3  = (const float*)d_in[21];
  const float* b3  = (const float*)d_in[22];
  float* out = (float*)d_out;

  char* wp = (char*)d_ws;
  auto carve = [&](size_t bytes) -> void* {
    void* p = (void*)wp;
    wp += (bytes + 255) & ~(size_t)255;
    return p;
  };
  bf16* wcombT = (bf16*)carve((size_t)NR * KA * 2);
  bf16* wbwgT  = (bf16*)carve((size_t)1024 * 512 * 2);
  bf16* w1T    = (bf16*)carve((size_t)256 * 512 * 2);
  float* sWa   = (float*)carve(512 * 4);
  float* sWe   = (float*)carve(512 * 4);
  float* baPad = (float*)carve(1024 * 4);
  bf16* xbuf   = (bf16*)carve((size_t)TSTEPS * BATCH * 64 * 2);
  float* cbuf  = (float*)carve((size_t)BATCH * HDIM * 4);
  bf16* hbuf   = (bf16*)carve((size_t)BATCH * HDIM * 2);
  bf16* hcur   = (bf16*)carve((size_t)BATCH * HDIM * 2);
  float* hWbG  = (float*)carve((size_t)BATCH * 1024 * 4);
  bf16* histWa = (bf16*)carve((size_t)16 * BATCH * HDIM * 2);
  bf16* histWe = (bf16*)carve((size_t)16 * BATCH * HDIM * 2);
  bf16* hd1    = (bf16*)carve((size_t)BATCH * 256 * 2);

  // ---- setup ----
  build_x_kernel<<<(TSTEPS * BATCH * 64) / 256, 256, 0, stream>>>(inputs, xbuf);
  pack_wcombT_kernel<<<(NR * KA + 255) / 256, 256, 0, stream>>>(Wx, Uh, Wt, WxT, Wa, We, wcombT);
  pack_t_kernel<<<(512 * 512) / 256, 256, 0, stream>>>(Wb, wbwgT, 512, 512);
  pack_t_kernel<<<(512 * 512) / 256, 256, 0, stream>>>(Wg, wbwgT + (size_t)512 * 512, 512, 512);
  pack_t_kernel<<<(256 * 512) / 256, 256, 0, stream>>>(W1, w1T, 256, 512);
  setup_misc_kernel<<<1, 512, 0, stream>>>(init_proj, Wa, We, ba, sWa, sWe, baPad);
  zero_state_kernel<<<(BATCH * HDIM) / 256, 256, 0, stream>>>(cbuf, hbuf);

  // ---- recurrence ----
  for (int t = 0; t < TSTEPS; ++t) {
    bf16* waSlot = histWa + (size_t)((t + 15) & 15) * BATCH * HDIM;
    bf16* weSlot = histWe + (size_t)((t + 15) & 15) * BATCH * HDIM;
    // fused: [x|td|h] @ Wcomb -> gates -> c,hcur + hWa,hWe history slots
    gemm1_fused_kernel<<<dim3(NR / 256, BATCH / 128), 256, 0, stream>>>(
        xbuf + (size_t)t * BATCH * 64, hbuf, wcombT, inputs, bv, WtT, bT,
        cbuf, hcur, waSlot, weSlot, t);
    // [hWb+ba | hWg] = h_cur @ [Wb|Wg] + [ba|0]
    gemm_glds_kernel<64, 128><<<dim3(1024 / 128, BATCH / 64), 256, 0, stream>>>(
        hcur, 512, 512, hcur, 512, wbwgT, 512, 0, hWbG, 1024, baPad, nullptr, 0, nullptr);
    attention_kernel<<<BATCH / 4, 256, 0, stream>>>(hWbG, sWa, sWe, va, bh, histWa, histWe,
                                                    hbuf, t);
  }

  // ---- head ----
  gemm_glds_kernel<64, 128><<<dim3(256 / 128, BATCH / 64), 256, 0, stream>>>(
      hbuf, 512, 512, hbuf, 512, w1T, 512, 3, nullptr, 0, nullptr, hd1, 256, b1);
  head_kernel<<<BATCH / 256, 256, 0, stream>>>(hd1, W2, b2, W3, b3, out);
}

// Round 5
// 1369.063 us; speedup vs baseline: 1.7834x; 1.1583x over previous
//
#include <hip/hip_runtime.h>
#include <hip/hip_bf16.h>

typedef __bf16 bf16;
typedef __attribute__((ext_vector_type(8))) __bf16 bf16x8;
typedef __attribute__((ext_vector_type(4))) float floatx4;

#define HDIM 512
#define BATCH 4096
#define TSTEPS 16
#define KA 576      // A width: 63 x-feats + td + 512 h
#define NR 4096     // GEMM1 out cols: role-interleaved, 8 roles x 512 h

typedef const __attribute__((address_space(1))) void gvoid;
typedef __attribute__((address_space(3))) void svoid;

__device__ __forceinline__ float ftanh(float x) {
  float xx = fminf(fmaxf(x, -15.f), 15.f);
  float t = __expf(2.f * xx);
  return (t - 1.f) / (t + 1.f);
}
__device__ __forceinline__ float fsigm(float x) { return 1.0f / (1.0f + __expf(-x)); }

__device__ __forceinline__ float waveAllSum(float v) {
#pragma unroll
  for (int off = 32; off > 0; off >>= 1) v += __shfl_xor(v, off, 64);
  return v;
}

// ---------------------------------------------------------------------------
// Fused GEMM1 + gates. A = [x_t(63) | td | h(512)], B = role-interleaved WcombT.
// n bits: h = (n>>7)*16 + (n&15), role = (n>>4)&7:
//   0..3 = zi,zf,zo,zc (td*Wt folded via A col63), 4 = tg, 5 = hWa, 6 = hWe, 7 = pad
// BM=64, BN=256, waves 2x2 (WM=32, WN=128): lane acc[i][role][r].
// 1-D grid of 1024 blocks, XCD-swizzled so each XCD owns 2 N-tiles (B L2 locality).
// ---------------------------------------------------------------------------
__global__ __launch_bounds__(256, 4)
void gemm1_fused_kernel(const bf16* __restrict__ A1, const bf16* __restrict__ A2,
                        const bf16* __restrict__ BT,
                        const float* __restrict__ tdT, const float* __restrict__ bvec,
                        const float* __restrict__ WtT, const float* __restrict__ bT,
                        float* __restrict__ cbuf, bf16* __restrict__ hcur,
                        bf16* __restrict__ waSlot, bf16* __restrict__ weSlot) {
  constexpr int BM = 64, BN = 256, BK = 32;
  constexpr int TM = 2, TN = 8;
  __shared__ __align__(16) bf16 As[BM * BK];
  __shared__ __align__(16) bf16 Bs[BN * BK];

  const int tid = threadIdx.x;
  const int lane = tid & 63;
  const int wv = tid >> 6;
  const int wy = wv >> 1;
  const int wx = wv & 1;
  const int quad = lane >> 4;
  const int lr = lane & 15;
  // XCD swizzle: 1024 blocks, bid%8 = XCD (heuristic); each XCD gets n-tiles {2x,2x+1}
  const int bid = blockIdx.x;
  const int xcd = bid & 7;
  const int p = bid >> 3;              // [0,128)
  const int n_idx = (xcd << 1) | (p >> 6);  // [0,16)
  const int m_idx = p & 63;            // [0,64)
  const int m0 = m_idx * BM;
  const int n0 = n_idx * BN;
  const int sw = quad ^ ((lr >> 1) & 3);
  const int srow = lane >> 2;
  const int cl = (lane & 3) ^ ((lane >> 3) & 3);

  floatx4 acc[TM][TN];
#pragma unroll
  for (int i = 0; i < TM; ++i)
#pragma unroll
    for (int j = 0; j < TN; ++j) {
      acc[i][j][0] = 0.f; acc[i][j][1] = 0.f; acc[i][j][2] = 0.f; acc[i][j][3] = 0.f;
    }

  for (int kt = 0; kt < KA / BK; ++kt) {
    const int kb = kt * BK;
    __syncthreads();
    {  // A: 64 rows = 4 groups of 16, 1 per wave
      const int rbase = wv * 16;
      const int r = rbase + srow;
      const int col = kb + cl * 8;
      const bf16* src = (col < 64) ? (A1 + (size_t)(m0 + r) * 64 + col)
                                   : (A2 + (size_t)(m0 + r) * 512 + (col - 64));
      __builtin_amdgcn_global_load_lds((gvoid*)src, (svoid*)&As[rbase * BK], 16, 0, 0);
    }
#pragma unroll
    for (int s = 0; s < 4; ++s) {  // B: 256 rows = 16 groups, 4 per wave
      const int rbase = (wv * 4 + s) * 16;
      const int r = rbase + srow;
      const bf16* src = BT + (size_t)(n0 + r) * KA + kb + cl * 8;
      __builtin_amdgcn_global_load_lds((gvoid*)src, (svoid*)&Bs[rbase * BK], 16, 0, 0);
    }
    __syncthreads();
    bf16x8 afr[TM];
    bf16x8 bfr[TN];
#pragma unroll
    for (int i = 0; i < TM; ++i)
      afr[i] = *reinterpret_cast<const bf16x8*>(&As[(wy * 32 + i * 16 + lr) * BK + sw * 8]);
#pragma unroll
    for (int j = 0; j < TN; ++j)
      bfr[j] = *reinterpret_cast<const bf16x8*>(&Bs[(wx * 128 + j * 16 + lr) * BK + sw * 8]);
#pragma unroll
    for (int i = 0; i < TM; ++i)
#pragma unroll
      for (int j = 0; j < TN; ++j)
        acc[i][j] = __builtin_amdgcn_mfma_f32_16x16x32_bf16(afr[i], bfr[j], acc[i][j], 0, 0, 0);
  }

  // ---- fused gate epilogue: lane owns h; roles are the j index ----
  const int h = (n_idx * 2 + wx) * 16 + lr;
  const float bvi = bvec[h], bvf = bvec[512 + h], bvo = bvec[1024 + h], bvc = bvec[1536 + h];
  const float wtt = WtT[h], bt_ = bT[h];
#pragma unroll
  for (int i = 0; i < TM; ++i) {
#pragma unroll
    for (int r = 0; r < 4; ++r) {
      const int m = m0 + wy * 32 + i * 16 + quad * 4 + r;
      const float td = tdT[m];
      const size_t o = (size_t)m * 512 + h;
      const float c_old = cbuf[o];
      const float i_ = fsigm(acc[i][0][r] + bvi);
      const float f_ = fsigm(acc[i][1][r] + bvf);
      const float o_ = fsigm(acc[i][2][r] + bvo);
      const float ch = ftanh(acc[i][3][r] + bvc);
      const float tg = fsigm(acc[i][4][r] + fsigm(td * wtt) + bt_);
      const float cn = f_ * c_old + (i_ + tg) * ch;
      cbuf[o] = cn;
      hcur[o] = (bf16)(o_ * ftanh(cn));
      waSlot[o] = (bf16)acc[i][5][r];
      weSlot[o] = (bf16)acc[i][6][r];
    }
  }
}

// ---------------------------------------------------------------------------
// Generic MFMA GEMM (glds staging).
// mode 0: f32 out (+colBias); mode 3: relu(v+cBias2) -> bf16 outBa
// mode 4: v+colBias -> bf16 outBa
// ---------------------------------------------------------------------------
template <int BM, int BN>
__global__ __launch_bounds__(256)
void gemm_glds_kernel(const bf16* __restrict__ A1, int ld1, int K1,
                      const bf16* __restrict__ A2, int ld2,
                      const bf16* __restrict__ BT, int K, int mode,
                      float* __restrict__ outF, int ldF, const float* __restrict__ colBias,
                      bf16* __restrict__ outBa, int ldBa, const float* __restrict__ cBias2) {
  constexpr int BK = 32;
  constexpr int WM = BM / 2;
  constexpr int WN = BN / 2;
  constexpr int TM = WM / 16;
  constexpr int TN = WN / 16;
  constexpr int AIW = BM / 64;
  constexpr int BIW = BN / 64;
  __shared__ __align__(16) bf16 As[BM * BK];
  __shared__ __align__(16) bf16 Bs[BN * BK];

  const int tid = threadIdx.x;
  const int lane = tid & 63;
  const int wv = tid >> 6;
  const int wy = wv >> 1;
  const int wx = wv & 1;
  const int quad = lane >> 4;
  const int lr = lane & 15;
  const int m0 = blockIdx.y * BM;
  const int n0 = blockIdx.x * BN;
  const int sw = quad ^ ((lr >> 1) & 3);
  const int srow = lane >> 2;
  const int cl = (lane & 3) ^ ((lane >> 3) & 3);

  floatx4 acc[TM][TN];
#pragma unroll
  for (int i = 0; i < TM; ++i)
#pragma unroll
    for (int j = 0; j < TN; ++j) {
      acc[i][j][0] = 0.f; acc[i][j][1] = 0.f; acc[i][j][2] = 0.f; acc[i][j][3] = 0.f;
    }

  const int kTiles = K / BK;
  for (int kt = 0; kt < kTiles; ++kt) {
    const int kb = kt * BK;
    __syncthreads();
#pragma unroll
    for (int s = 0; s < AIW; ++s) {
      const int rbase = (wv * AIW + s) * 16;
      const int r = rbase + srow;
      const int col = kb + cl * 8;
      const bf16* src = (col < K1) ? (A1 + (size_t)(m0 + r) * ld1 + col)
                                   : (A2 + (size_t)(m0 + r) * ld2 + (col - K1));
      __builtin_amdgcn_global_load_lds((gvoid*)src, (svoid*)&As[rbase * BK], 16, 0, 0);
    }
#pragma unroll
    for (int s = 0; s < BIW; ++s) {
      const int rbase = (wv * BIW + s) * 16;
      const int r = rbase + srow;
      const bf16* src = BT + (size_t)(n0 + r) * K + kb + cl * 8;
      __builtin_amdgcn_global_load_lds((gvoid*)src, (svoid*)&Bs[rbase * BK], 16, 0, 0);
    }
    __syncthreads();
    bf16x8 afr[TM];
    bf16x8 bfr[TN];
#pragma unroll
    for (int i = 0; i < TM; ++i)
      afr[i] = *reinterpret_cast<const bf16x8*>(&As[(wy * WM + i * 16 + lr) * BK + sw * 8]);
#pragma unroll
    for (int j = 0; j < TN; ++j)
      bfr[j] = *reinterpret_cast<const bf16x8*>(&Bs[(wx * WN + j * 16 + lr) * BK + sw * 8]);
#pragma unroll
    for (int i = 0; i < TM; ++i)
#pragma unroll
      for (int j = 0; j < TN; ++j)
        acc[i][j] = __builtin_amdgcn_mfma_f32_16x16x32_bf16(afr[i], bfr[j], acc[i][j], 0, 0, 0);
  }

#pragma unroll
  for (int i = 0; i < TM; ++i) {
#pragma unroll
    for (int j = 0; j < TN; ++j) {
#pragma unroll
      for (int r = 0; r < 4; ++r) {
        int m = m0 + wy * WM + i * 16 + quad * 4 + r;
        int n = n0 + wx * WN + j * 16 + lr;
        float v = acc[i][j][r];
        if (mode == 0) {
          if (colBias != nullptr) v += colBias[n];
          outF[(size_t)m * ldF + n] = v;
        } else if (mode == 4) {
          v += colBias[n];
          outBa[(size_t)m * ldBa + n] = (bf16)v;
        } else {  // mode 3
          v += cBias2[n];
          v = v > 0.f ? v : 0.f;
          outBa[(size_t)m * ldBa + n] = (bf16)v;
        }
      }
    }
  }
}

// ---------------------------------------------------------------------------
// Setup kernels (run every call; ws re-poisoned by harness)
// ---------------------------------------------------------------------------
// Role-interleaved WcombT[n][k]: h=(n>>7)*16+(n&15), role=(n>>4)&7
__global__ void pack_wcombT_kernel(const float* __restrict__ Wx, const float* __restrict__ Uh,
                                   const float* __restrict__ Wt, const float* __restrict__ WxT,
                                   const float* __restrict__ Wa, const float* __restrict__ We,
                                   bf16* __restrict__ out) {
  int idx = blockIdx.x * 256 + threadIdx.x;
  if (idx >= NR * KA) return;
  int n = idx / KA;
  int k = idx - n * KA;
  int h = (n >> 7) * 16 + (n & 15);
  int role = (n >> 4) & 7;
  float v = 0.f;
  if (k < 63) {
    if (role < 4) v = Wx[k * 2048 + role * 512 + h];
    else if (role == 4) v = WxT[k * 512 + h];
  } else if (k == 63) {
    if (role < 3) v = Wt[role * 512 + h];
  } else {
    int kh = k - 64;
    if (role < 4) v = Uh[kh * 2048 + role * 512 + h];
    else if (role == 5) v = Wa[kh * 512 + h];
    else if (role == 6) v = We[kh * 512 + h];
  }
  out[idx] = (bf16)v;
}

__global__ void pack_t_kernel(const float* __restrict__ in, bf16* __restrict__ out, int N, int K) {
  int idx = blockIdx.x * 256 + threadIdx.x;
  if (idx >= N * K) return;
  int n = idx / K;
  int j = idx - n * K;
  out[idx] = (bf16)in[(size_t)j * N + n];
}

// s = colsum(init_proj); sWa = s@Wa; sWe = s@We; baPad = [ba|0]
__global__ __launch_bounds__(512)
void setup_misc_kernel(const float* __restrict__ init_proj, const float* __restrict__ Wa,
                       const float* __restrict__ We, const float* __restrict__ ba,
                       float* __restrict__ sWa, float* __restrict__ sWe,
                       float* __restrict__ baPad) {
  __shared__ float s_sh[HDIM];
  int h = threadIdx.x;
  float acc = 0.f;
  for (int f = 0; f < 64; ++f) acc += init_proj[f * HDIM + h];
  s_sh[h] = acc;
  baPad[h] = ba[h];
  baPad[HDIM + h] = 0.f;
  __syncthreads();
  float a2 = 0.f, a3 = 0.f;
  for (int i = 0; i < HDIM; ++i) {
    a2 += s_sh[i] * Wa[i * HDIM + h];
    a3 += s_sh[i] * We[i * HDIM + h];
  }
  sWa[h] = a2;
  sWe[h] = a3;
}

__global__ void zero_state_kernel(float* __restrict__ c, bf16* __restrict__ h) {
  int idx = blockIdx.x * 256 + threadIdx.x;
  if (idx >= BATCH * HDIM) return;
  c[idx] = 0.f;
  h[idx] = (bf16)0.f;
}

// xbuf[t][b][64]: cols 0..62 = feats 1..63, col 63 = td; tdT[t][b] = td (f32)
__global__ void build_x_kernel(const float* __restrict__ inputs, bf16* __restrict__ xbuf,
                               float* __restrict__ tdT) {
  int idx = blockIdx.x * 256 + threadIdx.x;
  if (idx >= TSTEPS * BATCH * 64) return;
  int c = idx & 63;
  int bt = idx >> 6;
  int t = bt >> 12;
  int b = bt & 4095;
  float v;
  if (c < 63) {
    v = inputs[(size_t)b * 1024 + t * 64 + 1 + c];
  } else {
    v = inputs[(size_t)b * 1024 + t * 64];
    tdT[t * BATCH + b] = v;
  }
  xbuf[idx] = (bf16)v;
}

// attention + h_new epilogue; 4 waves/block, one batch row per wave
__global__ __launch_bounds__(256)
void attention_kernel(const bf16* __restrict__ hWbG,  // [B,1024] bf16: [hWb+ba | hWg]
                      const float* __restrict__ sWa, const float* __restrict__ sWe,
                      const float* __restrict__ va, const float* __restrict__ bh,
                      const bf16* __restrict__ histWa, const bf16* __restrict__ histWe,
                      bf16* __restrict__ hbuf, int k) {
  int b = blockIdx.x * 4 + (threadIdx.x >> 6);
  int lane = threadIdx.x & 63;
  float wb[8], sw_[8], vv[8];
  const bf16* wbp = hWbG + (size_t)b * 1024 + lane * 8;
  bf16x8 wbv = *reinterpret_cast<const bf16x8*>(wbp);
#pragma unroll
  for (int i = 0; i < 8; ++i) {
    wb[i] = (float)wbv[i];
    sw_[i] = sWa[lane * 8 + i];
    vv[i] = va[lane * 8 + i];
  }
  float p = 0.f;
#pragma unroll
  for (int i = 0; i < 8; ++i) p += vv[i] * ftanh(sw_[i] + wb[i]);
  float e_init = waveAllSum(p);

  float e[15];
#pragma unroll
  for (int j = 0; j < 15; ++j) {
    if (j < k) {
      bf16x8 hv = *reinterpret_cast<const bf16x8*>(
          histWa + ((size_t)j * BATCH + b) * HDIM + lane * 8);
      float q = 0.f;
#pragma unroll
      for (int i = 0; i < 8; ++i) q += vv[i] * ftanh((float)hv[i] + wb[i]);
      e[j] = waveAllSum(q);
    }
  }
  float mx = (k < 15) ? e_init : -1e30f;
#pragma unroll
  for (int j = 0; j < 15; ++j)
    if (j < k) mx = fmaxf(mx, e[j]);
  float winit = (k < 15) ? (float)(15 - k) * __expf(e_init - mx) : 0.f;
  float denom = winit;
  float w[15];
#pragma unroll
  for (int j = 0; j < 15; ++j)
    if (j < k) { w[j] = __expf(e[j] - mx); denom += w[j]; }
  float inv = 1.f / denom;
  float cx[8];
  float ai = winit * inv;
#pragma unroll
  for (int i = 0; i < 8; ++i) cx[i] = ai * sWe[lane * 8 + i];
#pragma unroll
  for (int j = 0; j < 15; ++j) {
    if (j < k) {
      bf16x8 hv = *reinterpret_cast<const bf16x8*>(
          histWe + ((size_t)j * BATCH + b) * HDIM + lane * 8);
      float aj = w[j] * inv;
#pragma unroll
      for (int i = 0; i < 8; ++i) cx[i] += aj * (float)hv[i];
    }
  }
  bf16x8 wgv = *reinterpret_cast<const bf16x8*>(wbp + 512);
  bf16x8 hnew;
#pragma unroll
  for (int i = 0; i < 8; ++i)
    hnew[i] = (bf16)ftanh(cx[i] + (float)wgv[i] + bh[lane * 8 + i]);
  *reinterpret_cast<bf16x8*>(hbuf + (size_t)b * HDIM + lane * 8) = hnew;
}

__global__ __launch_bounds__(256)
void head_kernel(const bf16* __restrict__ hd1, const float* __restrict__ W2,
                 const float* __restrict__ b2, const float* __restrict__ W3,
                 const float* __restrict__ b3, float* __restrict__ out) {
  __shared__ float W2s[256 * 32];
  __shared__ float b2s[32];
  __shared__ float W3s[64];
  __shared__ float b3s[2];
  for (int i = threadIdx.x; i < 256 * 32; i += 256) W2s[i] = W2[i];
  if (threadIdx.x < 32) b2s[threadIdx.x] = b2[threadIdx.x];
  if (threadIdx.x < 64) W3s[threadIdx.x] = W3[threadIdx.x];
  if (threadIdx.x < 2) b3s[threadIdx.x] = b3[threadIdx.x];
  __syncthreads();
  int row = blockIdx.x * 256 + threadIdx.x;
  float acc[32];
#pragma unroll
  for (int j = 0; j < 32; ++j) acc[j] = b2s[j];
  const bf16* hp = hd1 + (size_t)row * 256;
  for (int i = 0; i < 256; ++i) {
    float hv = (float)hp[i];
#pragma unroll
    for (int j = 0; j < 32; ++j) acc[j] += hv * W2s[i * 32 + j];
  }
  float l0 = b3s[0], l1 = b3s[1];
#pragma unroll
  for (int j = 0; j < 32; ++j) {
    float r = fmaxf(acc[j], 0.f);
    l0 += r * W3s[j * 2];
    l1 += r * W3s[j * 2 + 1];
  }
  float m = fmaxf(l0, l1);
  float e0 = __expf(l0 - m), e1 = __expf(l1 - m);
  float inv = 1.f / (e0 + e1);
  out[(size_t)row * 2] = e0 * inv;
  out[(size_t)row * 2 + 1] = e1 * inv;
}

// ---------------------------------------------------------------------------
extern "C" void kernel_launch(void* const* d_in, const int* in_sizes, int n_in,
                              void* d_out, int out_size, void* d_ws, size_t ws_size,
                              hipStream_t stream) {
  const float* inputs    = (const float*)d_in[0];
  const float* init_proj = (const float*)d_in[1];
  const float* Wx  = (const float*)d_in[3];
  const float* Uh  = (const float*)d_in[4];
  const float* Wt  = (const float*)d_in[5];
  const float* bv  = (const float*)d_in[6];
  const float* WxT = (const float*)d_in[7];
  const float* WtT = (const float*)d_in[8];
  const float* bT  = (const float*)d_in[9];
  const float* Wa  = (const float*)d_in[10];
  const float* Wb  = (const float*)d_in[11];
  const float* va  = (const float*)d_in[12];
  const float* ba  = (const float*)d_in[13];
  const float* We  = (const float*)d_in[14];
  const float* Wg  = (const float*)d_in[15];
  const float* bh  = (const float*)d_in[16];
  const float* W1  = (const float*)d_in[17];
  const float* b1  = (const float*)d_in[18];
  const float* W2  = (const float*)d_in[19];
  const float* b2  = (const float*)d_in[20];
  const float* W3  = (const float*)d_in[21];
  const float* b3  = (const float*)d_in[22];
  float* out = (float*)d_out;

  char* wp = (char*)d_ws;
  auto carve = [&](size_t bytes) -> void* {
    void* p = (void*)wp;
    wp += (bytes + 255) & ~(size_t)255;
    return p;
  };
  bf16* wcombT = (bf16*)carve((size_t)NR * KA * 2);
  bf16* wbwgT  = (bf16*)carve((size_t)1024 * 512 * 2);
  bf16* w1T    = (bf16*)carve((size_t)256 * 512 * 2);
  float* sWa   = (float*)carve(512 * 4);
  float* sWe   = (float*)carve(512 * 4);
  float* baPad = (float*)carve(1024 * 4);
  bf16* xbuf   = (bf16*)carve((size_t)TSTEPS * BATCH * 64 * 2);
  float* tdT   = (float*)carve((size_t)TSTEPS * BATCH * 4);
  float* cbuf  = (float*)carve((size_t)BATCH * HDIM * 4);
  bf16* hbuf   = (bf16*)carve((size_t)BATCH * HDIM * 2);
  bf16* hcur   = (bf16*)carve((size_t)BATCH * HDIM * 2);
  bf16* hWbG   = (bf16*)carve((size_t)BATCH * 1024 * 2);
  bf16* histWa = (bf16*)carve((size_t)16 * BATCH * HDIM * 2);
  bf16* histWe = (bf16*)carve((size_t)16 * BATCH * HDIM * 2);
  bf16* hd1    = (bf16*)carve((size_t)BATCH * 256 * 2);

  // ---- setup ----
  build_x_kernel<<<(TSTEPS * BATCH * 64) / 256, 256, 0, stream>>>(inputs, xbuf, tdT);
  pack_wcombT_kernel<<<(NR * KA + 255) / 256, 256, 0, stream>>>(Wx, Uh, Wt, WxT, Wa, We, wcombT);
  pack_t_kernel<<<(512 * 512) / 256, 256, 0, stream>>>(Wb, wbwgT, 512, 512);
  pack_t_kernel<<<(512 * 512) / 256, 256, 0, stream>>>(Wg, wbwgT + (size_t)512 * 512, 512, 512);
  pack_t_kernel<<<(256 * 512) / 256, 256, 0, stream>>>(W1, w1T, 256, 512);
  setup_misc_kernel<<<1, 512, 0, stream>>>(init_proj, Wa, We, ba, sWa, sWe, baPad);
  zero_state_kernel<<<(BATCH * HDIM) / 256, 256, 0, stream>>>(cbuf, hbuf);

  // ---- recurrence ----
  for (int t = 0; t < TSTEPS; ++t) {
    bf16* waSlot = histWa + (size_t)((t + 15) & 15) * BATCH * HDIM;
    bf16* weSlot = histWe + (size_t)((t + 15) & 15) * BATCH * HDIM;
    // fused: [x|td|h] @ Wcomb -> gates -> c,hcur + hWa,hWe history slots
    gemm1_fused_kernel<<<1024, 256, 0, stream>>>(
        xbuf + (size_t)t * BATCH * 64, hbuf, wcombT, tdT + (size_t)t * BATCH, bv, WtT, bT,
        cbuf, hcur, waSlot, weSlot);
    // [hWb+ba | hWg] = h_cur @ [Wb|Wg] + [ba|0]  (bf16 out)
    gemm_glds_kernel<64, 128><<<dim3(1024 / 128, BATCH / 64), 256, 0, stream>>>(
        hcur, 512, 512, hcur, 512, wbwgT, 512, 4, nullptr, 0, baPad, hWbG, 1024, nullptr);
    attention_kernel<<<BATCH / 4, 256, 0, stream>>>(hWbG, sWa, sWe, va, bh, histWa, histWe,
                                                    hbuf, t);
  }

  // ---- head ----
  gemm_glds_kernel<64, 128><<<dim3(256 / 128, BATCH / 64), 256, 0, stream>>>(
      hbuf, 512, 512, hbuf, 512, w1T, 512, 3, nullptr, 0, nullptr, hd1, 256, b1);
  head_kernel<<<BATCH / 256, 256, 0, stream>>>(hd1, W2, b2, W3, b3, out);
}

// Round 6
// 1335.620 us; speedup vs baseline: 1.8281x; 1.0250x over previous
//
#include <hip/hip_runtime.h>
#include <hip/hip_bf16.h>

typedef __bf16 bf16;
typedef __attribute__((ext_vector_type(8))) __bf16 bf16x8;
typedef __attribute__((ext_vector_type(4))) float floatx4;

#define HDIM 512
#define BATCH 4096
#define TSTEPS 16
#define KA 576      // A width: 63 x-feats + td + 512 h
#define NR 4096     // GEMM1 out cols: role-interleaved, 8 roles x 512 h

typedef const __attribute__((address_space(1))) void gvoid;
typedef __attribute__((address_space(3))) void svoid;

__device__ __forceinline__ float ftanh(float x) {
  float xx = fminf(fmaxf(x, -15.f), 15.f);
  float t = __expf(2.f * xx);
  return (t - 1.f) / (t + 1.f);
}
__device__ __forceinline__ float fsigm(float x) { return 1.0f / (1.0f + __expf(-x)); }

__device__ __forceinline__ float waveAllSum(float v) {
#pragma unroll
  for (int off = 32; off > 0; off >>= 1) v += __shfl_xor(v, off, 64);
  return v;
}

// ---------------------------------------------------------------------------
// Fused GEMM1 + gates. A = [x_t(63) | td | h(512)], B = role-interleaved WcombT.
// n bits: h = (n>>7)*16 + (n&15), role = (n>>4)&7:
//   0..3 = zi,zf,zo,zc (td*Wt folded via A col63), 4 = tg, 5 = hWa, 6 = hWe, 7 = pad
// BM=128, BN=128, waves 2x2 (WM=WN=64), TM=TN=4 (m97 golden LDS:MFMA ratio).
// A 128-col tile spans all 8 roles x 16 h: role = wx*4+j, h = (n0>>7)*16+lr.
// wx=1 waves pass tg to wx=0 waves through padded LDS (stride 17, conflict-free).
// 1024 blocks XCD-swizzled: each XCD owns 4 n-tiles (B slice 590 KB, L2-resident).
// ---------------------------------------------------------------------------
__global__ __launch_bounds__(256, 4)
void gemm1_fused_kernel(const bf16* __restrict__ A1, const bf16* __restrict__ A2,
                        const bf16* __restrict__ BT,
                        const float* __restrict__ tdT, const float* __restrict__ bvec,
                        const float* __restrict__ WtT, const float* __restrict__ bT,
                        float* __restrict__ cbuf, bf16* __restrict__ hcur,
                        bf16* __restrict__ waSlot, bf16* __restrict__ weSlot) {
  constexpr int BM = 128, BN = 128, BK = 32;
  constexpr int TM = 4, TN = 4;
  __shared__ __align__(16) bf16 As[BM * BK];
  __shared__ __align__(16) bf16 Bs[BN * BK];
  __shared__ float tgs[128 * 17];  // tg exchange, stride 17 -> conflict-free

  const int tid = threadIdx.x;
  const int lane = tid & 63;
  const int wv = tid >> 6;
  const int wy = wv >> 1;
  const int wx = wv & 1;
  const int quad = lane >> 4;
  const int lr = lane & 15;
  // XCD swizzle: bid%8 = XCD; each XCD owns 4 consecutive n-tiles
  const int bid = blockIdx.x;
  const int xcd = bid & 7;
  const int p = bid >> 3;               // [0,128)
  const int n_idx = (xcd << 2) | (p >> 5);  // [0,32)
  const int m_idx = p & 31;             // [0,32)
  const int m0 = m_idx * BM;
  const int n0 = n_idx * BN;
  const int sw = quad ^ ((lr >> 1) & 3);
  const int srow = lane >> 2;
  const int cl = (lane & 3) ^ ((lane >> 3) & 3);

  floatx4 acc[TM][TN];
#pragma unroll
  for (int i = 0; i < TM; ++i)
#pragma unroll
    for (int j = 0; j < TN; ++j) {
      acc[i][j][0] = 0.f; acc[i][j][1] = 0.f; acc[i][j][2] = 0.f; acc[i][j][3] = 0.f;
    }

  for (int kt = 0; kt < KA / BK; ++kt) {
    const int kb = kt * BK;
    __syncthreads();
#pragma unroll
    for (int s = 0; s < 2; ++s) {  // A: 128 rows = 8 groups of 16, 2 per wave
      const int rbase = (wv * 2 + s) * 16;
      const int r = rbase + srow;
      const int col = kb + cl * 8;
      const bf16* src = (col < 64) ? (A1 + (size_t)(m0 + r) * 64 + col)
                                   : (A2 + (size_t)(m0 + r) * 512 + (col - 64));
      __builtin_amdgcn_global_load_lds((gvoid*)src, (svoid*)&As[rbase * BK], 16, 0, 0);
    }
#pragma unroll
    for (int s = 0; s < 2; ++s) {  // B: 128 rows = 8 groups, 2 per wave
      const int rbase = (wv * 2 + s) * 16;
      const int r = rbase + srow;
      const bf16* src = BT + (size_t)(n0 + r) * KA + kb + cl * 8;
      __builtin_amdgcn_global_load_lds((gvoid*)src, (svoid*)&Bs[rbase * BK], 16, 0, 0);
    }
    __syncthreads();
    bf16x8 afr[TM];
    bf16x8 bfr[TN];
#pragma unroll
    for (int i = 0; i < TM; ++i)
      afr[i] = *reinterpret_cast<const bf16x8*>(&As[(wy * 64 + i * 16 + lr) * BK + sw * 8]);
#pragma unroll
    for (int j = 0; j < TN; ++j)
      bfr[j] = *reinterpret_cast<const bf16x8*>(&Bs[(wx * 64 + j * 16 + lr) * BK + sw * 8]);
#pragma unroll
    for (int i = 0; i < TM; ++i)
#pragma unroll
      for (int j = 0; j < TN; ++j)
        acc[i][j] = __builtin_amdgcn_mfma_f32_16x16x32_bf16(afr[i], bfr[j], acc[i][j], 0, 0, 0);
  }

  // ---- fused gate epilogue ----
  // wx=1 waves hold roles 4..7: j=0 -> tg (to LDS), j=1 -> hWa, j=2 -> hWe
  const int hcol = (n_idx >> 0) * 0 + ((n0 >> 7) * 16 + lr);
  if (wx == 1) {
#pragma unroll
    for (int i = 0; i < TM; ++i) {
#pragma unroll
      for (int r = 0; r < 4; ++r) {
        const int rl = wy * 64 + i * 16 + quad * 4 + r;
        const int m = m0 + rl;
        const size_t o = (size_t)m * 512 + hcol;
        tgs[rl * 17 + lr] = acc[i][0][r];
        waSlot[o] = (bf16)acc[i][1][r];
        weSlot[o] = (bf16)acc[i][2][r];
      }
    }
  }
  __syncthreads();
  if (wx == 0) {
    const float bvi = bvec[hcol], bvf = bvec[512 + hcol];
    const float bvo = bvec[1024 + hcol], bvc = bvec[1536 + hcol];
    const float wtt = WtT[hcol], bt_ = bT[hcol];
#pragma unroll
    for (int i = 0; i < TM; ++i) {
#pragma unroll
      for (int r = 0; r < 4; ++r) {
        const int rl = wy * 64 + i * 16 + quad * 4 + r;
        const int m = m0 + rl;
        const float td = tdT[m];
        const size_t o = (size_t)m * 512 + hcol;
        const float c_old = cbuf[o];
        const float i_ = fsigm(acc[i][0][r] + bvi);
        const float f_ = fsigm(acc[i][1][r] + bvf);
        const float o_ = fsigm(acc[i][2][r] + bvo);
        const float ch = ftanh(acc[i][3][r] + bvc);
        const float tg = fsigm(tgs[rl * 17 + lr] + fsigm(td * wtt) + bt_);
        const float cn = f_ * c_old + (i_ + tg) * ch;
        cbuf[o] = cn;
        hcur[o] = (bf16)(o_ * ftanh(cn));
      }
    }
  }
}

// ---------------------------------------------------------------------------
// Generic MFMA GEMM (glds staging).
// mode 0: f32 out (+colBias); mode 3: relu(v+cBias2) -> bf16 outBa
// mode 4: v+colBias -> bf16 outBa
// ---------------------------------------------------------------------------
template <int BM, int BN>
__global__ __launch_bounds__(256)
void gemm_glds_kernel(const bf16* __restrict__ A1, int ld1, int K1,
                      const bf16* __restrict__ A2, int ld2,
                      const bf16* __restrict__ BT, int K, int mode,
                      float* __restrict__ outF, int ldF, const float* __restrict__ colBias,
                      bf16* __restrict__ outBa, int ldBa, const float* __restrict__ cBias2) {
  constexpr int BK = 32;
  constexpr int WM = BM / 2;
  constexpr int WN = BN / 2;
  constexpr int TM = WM / 16;
  constexpr int TN = WN / 16;
  constexpr int AIW = BM / 64;
  constexpr int BIW = BN / 64;
  __shared__ __align__(16) bf16 As[BM * BK];
  __shared__ __align__(16) bf16 Bs[BN * BK];

  const int tid = threadIdx.x;
  const int lane = tid & 63;
  const int wv = tid >> 6;
  const int wy = wv >> 1;
  const int wx = wv & 1;
  const int quad = lane >> 4;
  const int lr = lane & 15;
  const int m0 = blockIdx.y * BM;
  const int n0 = blockIdx.x * BN;
  const int sw = quad ^ ((lr >> 1) & 3);
  const int srow = lane >> 2;
  const int cl = (lane & 3) ^ ((lane >> 3) & 3);

  floatx4 acc[TM][TN];
#pragma unroll
  for (int i = 0; i < TM; ++i)
#pragma unroll
    for (int j = 0; j < TN; ++j) {
      acc[i][j][0] = 0.f; acc[i][j][1] = 0.f; acc[i][j][2] = 0.f; acc[i][j][3] = 0.f;
    }

  const int kTiles = K / BK;
  for (int kt = 0; kt < kTiles; ++kt) {
    const int kb = kt * BK;
    __syncthreads();
#pragma unroll
    for (int s = 0; s < AIW; ++s) {
      const int rbase = (wv * AIW + s) * 16;
      const int r = rbase + srow;
      const int col = kb + cl * 8;
      const bf16* src = (col < K1) ? (A1 + (size_t)(m0 + r) * ld1 + col)
                                   : (A2 + (size_t)(m0 + r) * ld2 + (col - K1));
      __builtin_amdgcn_global_load_lds((gvoid*)src, (svoid*)&As[rbase * BK], 16, 0, 0);
    }
#pragma unroll
    for (int s = 0; s < BIW; ++s) {
      const int rbase = (wv * BIW + s) * 16;
      const int r = rbase + srow;
      const bf16* src = BT + (size_t)(n0 + r) * K + kb + cl * 8;
      __builtin_amdgcn_global_load_lds((gvoid*)src, (svoid*)&Bs[rbase * BK], 16, 0, 0);
    }
    __syncthreads();
    bf16x8 afr[TM];
    bf16x8 bfr[TN];
#pragma unroll
    for (int i = 0; i < TM; ++i)
      afr[i] = *reinterpret_cast<const bf16x8*>(&As[(wy * WM + i * 16 + lr) * BK + sw * 8]);
#pragma unroll
    for (int j = 0; j < TN; ++j)
      bfr[j] = *reinterpret_cast<const bf16x8*>(&Bs[(wx * WN + j * 16 + lr) * BK + sw * 8]);
#pragma unroll
    for (int i = 0; i < TM; ++i)
#pragma unroll
      for (int j = 0; j < TN; ++j)
        acc[i][j] = __builtin_amdgcn_mfma_f32_16x16x32_bf16(afr[i], bfr[j], acc[i][j], 0, 0, 0);
  }

#pragma unroll
  for (int i = 0; i < TM; ++i) {
#pragma unroll
    for (int j = 0; j < TN; ++j) {
#pragma unroll
      for (int r = 0; r < 4; ++r) {
        int m = m0 + wy * WM + i * 16 + quad * 4 + r;
        int n = n0 + wx * WN + j * 16 + lr;
        float v = acc[i][j][r];
        if (mode == 0) {
          if (colBias != nullptr) v += colBias[n];
          outF[(size_t)m * ldF + n] = v;
        } else if (mode == 4) {
          v += colBias[n];
          outBa[(size_t)m * ldBa + n] = (bf16)v;
        } else {  // mode 3
          v += cBias2[n];
          v = v > 0.f ? v : 0.f;
          outBa[(size_t)m * ldBa + n] = (bf16)v;
        }
      }
    }
  }
}

// ---------------------------------------------------------------------------
// Setup kernels (run every call; ws re-poisoned by harness)
// ---------------------------------------------------------------------------
// Role-interleaved WcombT[n][k]: h=(n>>7)*16+(n&15), role=(n>>4)&7
__global__ void pack_wcombT_kernel(const float* __restrict__ Wx, const float* __restrict__ Uh,
                                   const float* __restrict__ Wt, const float* __restrict__ WxT,
                                   const float* __restrict__ Wa, const float* __restrict__ We,
                                   bf16* __restrict__ out) {
  int idx = blockIdx.x * 256 + threadIdx.x;
  if (idx >= NR * KA) return;
  int n = idx / KA;
  int k = idx - n * KA;
  int h = (n >> 7) * 16 + (n & 15);
  int role = (n >> 4) & 7;
  float v = 0.f;
  if (k < 63) {
    if (role < 4) v = Wx[k * 2048 + role * 512 + h];
    else if (role == 4) v = WxT[k * 512 + h];
  } else if (k == 63) {
    if (role < 3) v = Wt[role * 512 + h];
  } else {
    int kh = k - 64;
    if (role < 4) v = Uh[kh * 2048 + role * 512 + h];
    else if (role == 5) v = Wa[kh * 512 + h];
    else if (role == 6) v = We[kh * 512 + h];
  }
  out[idx] = (bf16)v;
}

__global__ void pack_t_kernel(const float* __restrict__ in, bf16* __restrict__ out, int N, int K) {
  int idx = blockIdx.x * 256 + threadIdx.x;
  if (idx >= N * K) return;
  int n = idx / K;
  int j = idx - n * K;
  out[idx] = (bf16)in[(size_t)j * N + n];
}

// s = colsum(init_proj); sWa = s@Wa; sWe = s@We; baPad = [ba|0]
__global__ __launch_bounds__(512)
void setup_misc_kernel(const float* __restrict__ init_proj, const float* __restrict__ Wa,
                       const float* __restrict__ We, const float* __restrict__ ba,
                       float* __restrict__ sWa, float* __restrict__ sWe,
                       float* __restrict__ baPad) {
  __shared__ float s_sh[HDIM];
  int h = threadIdx.x;
  float acc = 0.f;
  for (int f = 0; f < 64; ++f) acc += init_proj[f * HDIM + h];
  s_sh[h] = acc;
  baPad[h] = ba[h];
  baPad[HDIM + h] = 0.f;
  __syncthreads();
  float a2 = 0.f, a3 = 0.f;
  for (int i = 0; i < HDIM; ++i) {
    a2 += s_sh[i] * Wa[i * HDIM + h];
    a3 += s_sh[i] * We[i * HDIM + h];
  }
  sWa[h] = a2;
  sWe[h] = a3;
}

__global__ void zero_state_kernel(float* __restrict__ c, bf16* __restrict__ h) {
  int idx = blockIdx.x * 256 + threadIdx.x;
  if (idx >= BATCH * HDIM) return;
  c[idx] = 0.f;
  h[idx] = (bf16)0.f;
}

// xbuf[t][b][64]: cols 0..62 = feats 1..63, col 63 = td; tdT[t][b] = td (f32)
__global__ void build_x_kernel(const float* __restrict__ inputs, bf16* __restrict__ xbuf,
                               float* __restrict__ tdT) {
  int idx = blockIdx.x * 256 + threadIdx.x;
  if (idx >= TSTEPS * BATCH * 64) return;
  int c = idx & 63;
  int bt = idx >> 6;
  int t = bt >> 12;
  int b = bt & 4095;
  float v;
  if (c < 63) {
    v = inputs[(size_t)b * 1024 + t * 64 + 1 + c];
  } else {
    v = inputs[(size_t)b * 1024 + t * 64];
    tdT[t * BATCH + b] = v;
  }
  xbuf[idx] = (bf16)v;
}

// attention + h_new epilogue; 4 waves/block, one batch row per wave
__global__ __launch_bounds__(256)
void attention_kernel(const bf16* __restrict__ hWbG,  // [B,1024] bf16: [hWb+ba | hWg]
                      const float* __restrict__ sWa, const float* __restrict__ sWe,
                      const float* __restrict__ va, const float* __restrict__ bh,
                      const bf16* __restrict__ histWa, const bf16* __restrict__ histWe,
                      bf16* __restrict__ hbuf, int k) {
  int b = blockIdx.x * 4 + (threadIdx.x >> 6);
  int lane = threadIdx.x & 63;
  float wb[8], sw_[8], vv[8];
  const bf16* wbp = hWbG + (size_t)b * 1024 + lane * 8;
  bf16x8 wbv = *reinterpret_cast<const bf16x8*>(wbp);
#pragma unroll
  for (int i = 0; i < 8; ++i) {
    wb[i] = (float)wbv[i];
    sw_[i] = sWa[lane * 8 + i];
    vv[i] = va[lane * 8 + i];
  }
  float p = 0.f;
#pragma unroll
  for (int i = 0; i < 8; ++i) p += vv[i] * ftanh(sw_[i] + wb[i]);
  float e_init = waveAllSum(p);

  float e[15];
#pragma unroll
  for (int j = 0; j < 15; ++j) {
    if (j < k) {
      bf16x8 hv = *reinterpret_cast<const bf16x8*>(
          histWa + ((size_t)j * BATCH + b) * HDIM + lane * 8);
      float q = 0.f;
#pragma unroll
      for (int i = 0; i < 8; ++i) q += vv[i] * ftanh((float)hv[i] + wb[i]);
      e[j] = waveAllSum(q);
    }
  }
  float mx = (k < 15) ? e_init : -1e30f;
#pragma unroll
  for (int j = 0; j < 15; ++j)
    if (j < k) mx = fmaxf(mx, e[j]);
  float winit = (k < 15) ? (float)(15 - k) * __expf(e_init - mx) : 0.f;
  float denom = winit;
  float w[15];
#pragma unroll
  for (int j = 0; j < 15; ++j)
    if (j < k) { w[j] = __expf(e[j] - mx); denom += w[j]; }
  float inv = 1.f / denom;
  float cx[8];
  float ai = winit * inv;
#pragma unroll
  for (int i = 0; i < 8; ++i) cx[i] = ai * sWe[lane * 8 + i];
#pragma unroll
  for (int j = 0; j < 15; ++j) {
    if (j < k) {
      bf16x8 hv = *reinterpret_cast<const bf16x8*>(
          histWe + ((size_t)j * BATCH + b) * HDIM + lane * 8);
      float aj = w[j] * inv;
#pragma unroll
      for (int i = 0; i < 8; ++i) cx[i] += aj * (float)hv[i];
    }
  }
  bf16x8 wgv = *reinterpret_cast<const bf16x8*>(wbp + 512);
  bf16x8 hnew;
#pragma unroll
  for (int i = 0; i < 8; ++i)
    hnew[i] = (bf16)ftanh(cx[i] + (float)wgv[i] + bh[lane * 8 + i]);
  *reinterpret_cast<bf16x8*>(hbuf + (size_t)b * HDIM + lane * 8) = hnew;
}

__global__ __launch_bounds__(256)
void head_kernel(const bf16* __restrict__ hd1, const float* __restrict__ W2,
                 const float* __restrict__ b2, const float* __restrict__ W3,
                 const float* __restrict__ b3, float* __restrict__ out) {
  __shared__ float W2s[256 * 32];
  __shared__ float b2s[32];
  __shared__ float W3s[64];
  __shared__ float b3s[2];
  for (int i = threadIdx.x; i < 256 * 32; i += 256) W2s[i] = W2[i];
  if (threadIdx.x < 32) b2s[threadIdx.x] = b2[threadIdx.x];
  if (threadIdx.x < 64) W3s[threadIdx.x] = W3[threadIdx.x];
  if (threadIdx.x < 2) b3s[threadIdx.x] = b3[threadIdx.x];
  __syncthreads();
  int row = blockIdx.x * 256 + threadIdx.x;
  float acc[32];
#pragma unroll
  for (int j = 0; j < 32; ++j) acc[j] = b2s[j];
  const bf16* hp = hd1 + (size_t)row * 256;
  for (int i = 0; i < 256; ++i) {
    float hv = (float)hp[i];
#pragma unroll
    for (int j = 0; j < 32; ++j) acc[j] += hv * W2s[i * 32 + j];
  }
  float l0 = b3s[0], l1 = b3s[1];
#pragma unroll
  for (int j = 0; j < 32; ++j) {
    float r = fmaxf(acc[j], 0.f);
    l0 += r * W3s[j * 2];
    l1 += r * W3s[j * 2 + 1];
  }
  float m = fmaxf(l0, l1);
  float e0 = __expf(l0 - m), e1 = __expf(l1 - m);
  float inv = 1.f / (e0 + e1);
  out[(size_t)row * 2] = e0 * inv;
  out[(size_t)row * 2 + 1] = e1 * inv;
}

// ---------------------------------------------------------------------------
extern "C" void kernel_launch(void* const* d_in, const int* in_sizes, int n_in,
                              void* d_out, int out_size, void* d_ws, size_t ws_size,
                              hipStream_t stream) {
  const float* inputs    = (const float*)d_in[0];
  const float* init_proj = (const float*)d_in[1];
  const float* Wx  = (const float*)d_in[3];
  const float* Uh  = (const float*)d_in[4];
  const float* Wt  = (const float*)d_in[5];
  const float* bv  = (const float*)d_in[6];
  const float* WxT = (const float*)d_in[7];
  const float* WtT = (const float*)d_in[8];
  const float* bT  = (const float*)d_in[9];
  const float* Wa  = (const float*)d_in[10];
  const float* Wb  = (const float*)d_in[11];
  const float* va  = (const float*)d_in[12];
  const float* ba  = (const float*)d_in[13];
  const float* We  = (const float*)d_in[14];
  const float* Wg  = (const float*)d_in[15];
  const float* bh  = (const float*)d_in[16];
  const float* W1  = (const float*)d_in[17];
  const float* b1  = (const float*)d_in[18];
  const float* W2  = (const float*)d_in[19];
  const float* b2  = (const float*)d_in[20];
  const float* W3  = (const float*)d_in[21];
  const float* b3  = (const float*)d_in[22];
  float* out = (float*)d_out;

  char* wp = (char*)d_ws;
  auto carve = [&](size_t bytes) -> void* {
    void* p = (void*)wp;
    wp += (bytes + 255) & ~(size_t)255;
    return p;
  };
  bf16* wcombT = (bf16*)carve((size_t)NR * KA * 2);
  bf16* wbwgT  = (bf16*)carve((size_t)1024 * 512 * 2);
  bf16* w1T    = (bf16*)carve((size_t)256 * 512 * 2);
  float* sWa   = (float*)carve(512 * 4);
  float* sWe   = (float*)carve(512 * 4);
  float* baPad = (float*)carve(1024 * 4);
  bf16* xbuf   = (bf16*)carve((size_t)TSTEPS * BATCH * 64 * 2);
  float* tdT   = (float*)carve((size_t)TSTEPS * BATCH * 4);
  float* cbuf  = (float*)carve((size_t)BATCH * HDIM * 4);
  bf16* hbuf   = (bf16*)carve((size_t)BATCH * HDIM * 2);
  bf16* hcur   = (bf16*)carve((size_t)BATCH * HDIM * 2);
  bf16* hWbG   = (bf16*)carve((size_t)BATCH * 1024 * 2);
  bf16* histWa = (bf16*)carve((size_t)16 * BATCH * HDIM * 2);
  bf16* histWe = (bf16*)carve((size_t)16 * BATCH * HDIM * 2);
  bf16* hd1    = (bf16*)carve((size_t)BATCH * 256 * 2);

  // ---- setup ----
  build_x_kernel<<<(TSTEPS * BATCH * 64) / 256, 256, 0, stream>>>(inputs, xbuf, tdT);
  pack_wcombT_kernel<<<(NR * KA + 255) / 256, 256, 0, stream>>>(Wx, Uh, Wt, WxT, Wa, We, wcombT);
  pack_t_kernel<<<(512 * 512) / 256, 256, 0, stream>>>(Wb, wbwgT, 512, 512);
  pack_t_kernel<<<(512 * 512) / 256, 256, 0, stream>>>(Wg, wbwgT + (size_t)512 * 512, 512, 512);
  pack_t_kernel<<<(256 * 512) / 256, 256, 0, stream>>>(W1, w1T, 256, 512);
  setup_misc_kernel<<<1, 512, 0, stream>>>(init_proj, Wa, We, ba, sWa, sWe, baPad);
  zero_state_kernel<<<(BATCH * HDIM) / 256, 256, 0, stream>>>(cbuf, hbuf);

  // ---- recurrence ----
  for (int t = 0; t < TSTEPS; ++t) {
    bf16* waSlot = histWa + (size_t)((t + 15) & 15) * BATCH * HDIM;
    bf16* weSlot = histWe + (size_t)((t + 15) & 15) * BATCH * HDIM;
    // fused: [x|td|h] @ Wcomb -> gates -> c,hcur + hWa,hWe history slots
    gemm1_fused_kernel<<<1024, 256, 0, stream>>>(
        xbuf + (size_t)t * BATCH * 64, hbuf, wcombT, tdT + (size_t)t * BATCH, bv, WtT, bT,
        cbuf, hcur, waSlot, weSlot);
    // [hWb+ba | hWg] = h_cur @ [Wb|Wg] + [ba|0]  (bf16 out)
    gemm_glds_kernel<64, 128><<<dim3(1024 / 128, BATCH / 64), 256, 0, stream>>>(
        hcur, 512, 512, hcur, 512, wbwgT, 512, 4, nullptr, 0, baPad, hWbG, 1024, nullptr);
    attention_kernel<<<BATCH / 4, 256, 0, stream>>>(hWbG, sWa, sWe, va, bh, histWa, histWe,
                                                    hbuf, t);
  }

  // ---- head ----
  gemm_glds_kernel<64, 128><<<dim3(256 / 128, BATCH / 64), 256, 0, stream>>>(
      hbuf, 512, 512, hbuf, 512, w1T, 512, 3, nullptr, 0, nullptr, hd1, 256, b1);
  head_kernel<<<BATCH / 256, 256, 0, stream>>>(hd1, W2, b2, W3, b3, out);
}